// Round 1
// baseline (351.072 us; speedup 1.0000x reference)
//
#include <hip/hip_runtime.h>

typedef unsigned short u16;
typedef unsigned int u32;
typedef __attribute__((ext_vector_type(8))) short bf16x8_t;
typedef __attribute__((ext_vector_type(4))) float f32x4_t;

// Problem constants: B=4, S=4096, H=1024, N=16, D=64, K-pool=64
// All GEMMs are [M x 1024] x [1024 x 1024].

__device__ __forceinline__ u16 f2bf(float f) {
  union { float f; u32 u; } a; a.f = f;
  u32 u = a.u;
  u32 r = (u + 0x7FFFu + ((u >> 16) & 1u)) >> 16;  // RNE
  return (u16)r;
}
__device__ __forceinline__ float bf2f(u16 x) {
  union { u32 u; float f; } a; a.u = ((u32)x) << 16; return a.f;
}

__device__ __forceinline__ void async_load16(const void* g, void* l) {
  __builtin_amdgcn_global_load_lds(
      (const __attribute__((address_space(1))) void*)g,
      (__attribute__((address_space(3))) void*)l, 16, 0, 0);
}

// ---------------- weight transpose: W[1024][1024] fp32 -> WT[1024][1024] bf16 ----------------
__global__ __launch_bounds__(256) void transpose_w(const float* __restrict__ W,
                                                   u16* __restrict__ WT) {
  __shared__ float tile[64][65];
  const int tr = blockIdx.x * 64;
  const int tc = blockIdx.y * 64;
  const int t = threadIdx.x;
#pragma unroll
  for (int i = 0; i < 16; ++i) {
    int idx = i * 256 + t;
    int r = idx >> 6, c = idx & 63;
    tile[r][c] = W[(size_t)(tr + r) * 1024 + tc + c];
  }
  __syncthreads();
#pragma unroll
  for (int i = 0; i < 16; ++i) {
    int idx = i * 256 + t;
    int r = idx >> 6, c = idx & 63;
    WT[(size_t)(tc + r) * 1024 + tr + c] = f2bf(tile[c][r]);
  }
}

// ---------------- downsample: x[B,S,H] -> xd[B*64, H] bf16 (mean over 64 rows) ----------------
__global__ __launch_bounds__(256) void downsample(const float* __restrict__ x,
                                                  u16* __restrict__ xd) {
  const int h = blockIdx.y * 256 + threadIdx.x;
  const int bkk = blockIdx.x;  // b*64 + kk
  const float* p = x + (size_t)bkk * 65536 + h;  // (b*64+kk)*64*1024
  float s = 0.f;
#pragma unroll
  for (int j = 0; j < 64; ++j) s += p[(size_t)j * 1024];
  xd[(size_t)bkk * 1024 + h] = f2bf(s * 0.015625f);
}

// ---------------- GEMM: C[M,1024] = A[M,1024] @ BT[1024,1024]^T + bias ----------------
// A_BF16: A is bf16 (staged via global_load_lds) else fp32 (reg-staged + converted)
// C_BF16: C written as bf16 else fp32
template <bool A_BF16, bool C_BF16>
__global__ __launch_bounds__(256) void gemm_bt(const void* __restrict__ Av,
                                               const u16* __restrict__ BT,
                                               const float* __restrict__ bias,
                                               void* __restrict__ Cv, int M) {
  constexpr int K = 1024, N = 1024, TM = 128, BK = 32;
  __shared__ u16 sA[TM * BK];
  __shared__ u16 sB[TM * BK];
  const int t = threadIdx.x;
  const int lane = t & 63;
  const int w = t >> 6;
  const int wr = w >> 1, wc = w & 1;
  const int m0 = blockIdx.x * TM;
  const int n0 = blockIdx.y * TM;
  const int c16 = lane & 15, r16 = lane >> 4;

  f32x4_t acc[4][4] = {};

  for (int k0 = 0; k0 < K; k0 += BK) {
    if constexpr (A_BF16) {
      const u16* A = (const u16*)Av;
#pragma unroll
      for (int i = 0; i < 2; ++i) {
        int c = i * 256 + t;
        int row = c >> 2, ch = c & 3;
        async_load16(A + (size_t)(m0 + row) * K + k0 + ch * 8,
                     (char*)sA + (i * 256 + w * 64) * 16);
      }
    } else {
      const float* A = (const float*)Av;
#pragma unroll
      for (int i = 0; i < 4; ++i) {
        int c = i * 256 + t;
        int row = c >> 3, ch = c & 7;
        const float4 v = *(const float4*)(A + (size_t)(m0 + row) * K + k0 + ch * 4);
        ushort4 bv;
        bv.x = f2bf(v.x); bv.y = f2bf(v.y); bv.z = f2bf(v.z); bv.w = f2bf(v.w);
        *(ushort4*)&sA[row * BK + ch * 4] = bv;
      }
    }
#pragma unroll
    for (int i = 0; i < 2; ++i) {
      int c = i * 256 + t;
      int row = c >> 2, ch = c & 3;
      async_load16(BT + (size_t)(n0 + row) * K + k0 + ch * 8,
                   (char*)sB + (i * 256 + w * 64) * 16);
    }
    __syncthreads();

    bf16x8_t af[4], bfv[4];
#pragma unroll
    for (int m = 0; m < 4; ++m)
      af[m] = *(const bf16x8_t*)&sA[(wr * 64 + m * 16 + c16) * BK + r16 * 8];
#pragma unroll
    for (int n = 0; n < 4; ++n)
      bfv[n] = *(const bf16x8_t*)&sB[(wc * 64 + n * 16 + c16) * BK + r16 * 8];
#pragma unroll
    for (int m = 0; m < 4; ++m)
#pragma unroll
      for (int n = 0; n < 4; ++n)
        acc[m][n] = __builtin_amdgcn_mfma_f32_16x16x32_bf16(af[m], bfv[n], acc[m][n], 0, 0, 0);
    __syncthreads();
  }

#pragma unroll
  for (int m = 0; m < 4; ++m) {
    const int row0 = m0 + wr * 64 + m * 16 + r16 * 4;
#pragma unroll
    for (int n = 0; n < 4; ++n) {
      const int col = n0 + wc * 64 + n * 16 + c16;
      const float bv = bias[col];
#pragma unroll
      for (int i = 0; i < 4; ++i) {
        const float val = acc[m][n][i] + bv;
        if constexpr (C_BF16)
          ((u16*)Cv)[(size_t)(row0 + i) * N + col] = f2bf(val);
        else
          ((float*)Cv)[(size_t)(row0 + i) * N + col] = val;
      }
    }
  }
}

// ---------------- pooled attention ----------------
// q: bf16 [B*S, 1024] (layout (b,s),(n,d));  kd,vd: fp32 [B*64, 1024]
// av: bf16 [B*S, 1024] = softmax(q . kd^T / 8) @ vd, per (b,n)
__global__ __launch_bounds__(256) void attn_kernel(const u16* __restrict__ qb,
                                                   const float* __restrict__ kdp,
                                                   const float* __restrict__ vdp,
                                                   u16* __restrict__ av) {
  __shared__ float skd[64][65];
  __shared__ float svd[64][65];
  __shared__ float sq[4][64][4];
  __shared__ float sp[4][64][4];
  const int t = threadIdx.x;
  const int lane = t & 63;
  const int w = t >> 6;
  const int n = blockIdx.y, b = blockIdx.z;
  const int sbase = blockIdx.x * 128;
  const int c16 = lane & 15, r16 = lane >> 4;

#pragma unroll
  for (int i = 0; i < 16; ++i) {
    int idx = i * 256 + t;
    int kk = idx >> 6, d = idx & 63;
    size_t off = (size_t)(b * 64 + kk) * 1024 + n * 64 + d;
    skd[kk][d] = kdp[off];
    svd[kk][d] = vdp[off];
  }
  __syncthreads();

  for (int g = 0; g < 8; ++g) {
    const int s0 = sbase + w * 32 + g * 4;
    // load q rows s0..s0+3: lane covers (row r16, dims c16*4..+3)
    const u16* qp = qb + (size_t)(b * 4096 + s0 + r16) * 1024 + n * 64 + c16 * 4;
    ushort4 qv = *(const ushort4*)qp;
    sq[w][c16 * 4 + 0][r16] = bf2f(qv.x);
    sq[w][c16 * 4 + 1][r16] = bf2f(qv.y);
    sq[w][c16 * 4 + 2][r16] = bf2f(qv.z);
    sq[w][c16 * 4 + 3][r16] = bf2f(qv.w);
    asm volatile("s_waitcnt lgkmcnt(0)" ::: "memory");

    // scores: lane = k
    float sc0 = 0, sc1 = 0, sc2 = 0, sc3 = 0;
#pragma unroll 8
    for (int d = 0; d < 64; ++d) {
      float kv = skd[lane][d];
      float4 qq = *(const float4*)&sq[w][d][0];
      sc0 += kv * qq.x; sc1 += kv * qq.y; sc2 += kv * qq.z; sc3 += kv * qq.w;
    }
    float scr[4] = {sc0, sc1, sc2, sc3};
    float pr[4];
#pragma unroll
    for (int r = 0; r < 4; ++r) {
      float x = scr[r] * 0.125f;
      float mx = x;
#pragma unroll
      for (int off = 32; off > 0; off >>= 1) mx = fmaxf(mx, __shfl_xor(mx, off));
      float e = __expf(x - mx);
      float ss = e;
#pragma unroll
      for (int off = 32; off > 0; off >>= 1) ss += __shfl_xor(ss, off);
      pr[r] = e / ss;
    }
    sp[w][lane][0] = pr[0];
    sp[w][lane][1] = pr[1];
    sp[w][lane][2] = pr[2];
    sp[w][lane][3] = pr[3];
    asm volatile("s_waitcnt lgkmcnt(0)" ::: "memory");

    // PV: lane = d
    float a0 = 0, a1 = 0, a2 = 0, a3 = 0;
#pragma unroll 8
    for (int k = 0; k < 64; ++k) {
      float vv = svd[k][lane];
      float4 pp = *(const float4*)&sp[w][k][0];
      a0 += pp.x * vv; a1 += pp.y * vv; a2 += pp.z * vv; a3 += pp.w * vv;
    }
    float ar[4] = {a0, a1, a2, a3};
#pragma unroll
    for (int r = 0; r < 4; ++r)
      av[(size_t)(b * 4096 + s0 + r) * 1024 + n * 64 + lane] = f2bf(ar[r]);
  }
}

extern "C" void kernel_launch(void* const* d_in, const int* in_sizes, int n_in,
                              void* d_out, int out_size, void* d_ws, size_t ws_size,
                              hipStream_t stream) {
  (void)in_sizes; (void)n_in; (void)out_size; (void)ws_size;
  const float* query = (const float*)d_in[0];
  const float* key   = (const float*)d_in[1];
  const float* value = (const float*)d_in[2];
  const float* Wq = (const float*)d_in[3];
  const float* bq = (const float*)d_in[4];
  const float* Wk = (const float*)d_in[5];
  const float* bk = (const float*)d_in[6];
  const float* Wv = (const float*)d_in[7];
  const float* bv = (const float*)d_in[8];
  const float* Wo = (const float*)d_in[9];
  const float* bo = (const float*)d_in[10];
  float* out = (float*)d_out;

  char* ws = (char*)d_ws;
  const size_t MB = 1024 * 1024;
  u16* WqT    = (u16*)(ws + 0 * MB);            // 2MB bf16 [nd][h]
  u16* WkT    = (u16*)(ws + 2 * MB);            // 2MB
  u16* WvT    = (u16*)(ws + 4 * MB);            // 2MB
  u16* WoT    = (u16*)(ws + 6 * MB);            // 2MB bf16 [h][nd]
  u16* keyd   = (u16*)(ws + 8 * MB);            // 0.5MB bf16 [256][1024]
  u16* valued = (u16*)(ws + 8 * MB + 512 * 1024);
  float* kdp  = (float*)(ws + 9 * MB);          // 1MB fp32 [256][1024]
  float* vdp  = (float*)(ws + 10 * MB);         // 1MB
  u16* avb    = (u16*)(ws + 11 * MB);           // 32MB bf16 [16384][1024]
  u16* qbuf   = (u16*)d_out;                    // 32MB scratch inside 64MB d_out

  dim3 blk(256);

  // 1) weight transposes (fp32 -> bf16, transposed for gemm_bt's B^T layout)
  transpose_w<<<dim3(16, 16), blk, 0, stream>>>(Wq, WqT);
  transpose_w<<<dim3(16, 16), blk, 0, stream>>>(Wk, WkT);
  transpose_w<<<dim3(16, 16), blk, 0, stream>>>(Wv, WvT);
  transpose_w<<<dim3(16, 16), blk, 0, stream>>>(Wo, WoT);

  // 2) downsample key/value BEFORE projection (mean commutes with linear proj)
  downsample<<<dim3(256, 4), blk, 0, stream>>>(key, keyd);
  downsample<<<dim3(256, 4), blk, 0, stream>>>(value, valued);

  // 3) kd = keyd @ Wk + bk ; vd = valued @ Wv + bv   (tiny GEMMs, fp32 out)
  gemm_bt<true, false><<<dim3(2, 8), blk, 0, stream>>>(keyd, WkT, bk, kdp, 256);
  gemm_bt<true, false><<<dim3(2, 8), blk, 0, stream>>>(valued, WvT, bv, vdp, 256);

  // 4) q = query @ Wq + bq  (bf16 out, stashed in d_out)
  gemm_bt<false, true><<<dim3(128, 8), blk, 0, stream>>>(query, WqT, bq, qbuf, 16384);

  // 5) pooled attention -> a_v (bf16)
  attn_kernel<<<dim3(32, 16, 4), blk, 0, stream>>>(qbuf, kdp, vdp, avb);

  // 6) out = a_v @ Wo + bo  (fp32 into d_out)
  gemm_bt<true, false><<<dim3(128, 8), blk, 0, stream>>>(avb, WoT, bo, out, 16384);
}

// Round 2
// 257.714 us; speedup vs baseline: 1.3623x; 1.3623x over previous
//
#include <hip/hip_runtime.h>

typedef unsigned short u16;
typedef unsigned int u32;
typedef __attribute__((ext_vector_type(8))) short bf16x8_t;
typedef __attribute__((ext_vector_type(4))) float f32x4_t;

// Problem constants: B=4, S=4096, H=1024, N=16, D=64, K-pool=64

__device__ __forceinline__ u16 f2bf(float f) {
  union { float f; u32 u; } a; a.f = f;
  u32 u = a.u;
  u32 r = (u + 0x7FFFu + ((u >> 16) & 1u)) >> 16;  // RNE
  return (u16)r;
}
__device__ __forceinline__ float bf2f(u16 x) {
  union { u32 u; float f; } a; a.u = ((u32)x) << 16; return a.f;
}

__device__ __forceinline__ void async_load16(const void* g, void* l) {
  __builtin_amdgcn_global_load_lds(
      (const __attribute__((address_space(1))) void*)g,
      (__attribute__((address_space(3))) void*)l, 16, 0, 0);
}

// ---------------- fused weight transposes: 4x W[1024][1024] fp32 -> WT bf16 ----------------
__global__ __launch_bounds__(256) void transpose_w4(const float* __restrict__ W0,
                                                    const float* __restrict__ W1,
                                                    const float* __restrict__ W2,
                                                    const float* __restrict__ W3,
                                                    u16* __restrict__ T0, u16* __restrict__ T1,
                                                    u16* __restrict__ T2, u16* __restrict__ T3) {
  const int z = blockIdx.z;
  const float* W = (z == 0) ? W0 : (z == 1) ? W1 : (z == 2) ? W2 : W3;
  u16* WT = (z == 0) ? T0 : (z == 1) ? T1 : (z == 2) ? T2 : T3;
  __shared__ float tile[64][65];
  const int tr = blockIdx.x * 64;
  const int tc = blockIdx.y * 64;
  const int t = threadIdx.x;
#pragma unroll
  for (int i = 0; i < 16; ++i) {
    int idx = i * 256 + t;
    int r = idx >> 6, c = idx & 63;
    tile[r][c] = W[(size_t)(tr + r) * 1024 + tc + c];
  }
  __syncthreads();
#pragma unroll
  for (int i = 0; i < 16; ++i) {
    int idx = i * 256 + t;
    int r = idx >> 6, c = idx & 63;
    WT[(size_t)(tc + r) * 1024 + tr + c] = f2bf(tile[c][r]);
  }
}

// ---------------- fused downsample: key,value [B,S,H] -> bf16 [B*64, H] ----------------
__global__ __launch_bounds__(256) void downsample2(const float* __restrict__ key,
                                                   const float* __restrict__ value,
                                                   u16* __restrict__ keyd,
                                                   u16* __restrict__ valued) {
  const float* x = blockIdx.z ? value : key;
  u16* xd = blockIdx.z ? valued : keyd;
  const int h = blockIdx.y * 256 + threadIdx.x;
  const int bkk = blockIdx.x;
  const float* p = x + (size_t)bkk * 65536 + h;
  float s = 0.f;
#pragma unroll
  for (int j = 0; j < 64; ++j) s += p[(size_t)j * 1024];
  xd[(size_t)bkk * 1024 + h] = f2bf(s * 0.015625f);
}

// ---------------- GEMM: C[M,1024] = A[M,1024] @ BT[1024,1024]^T + bias ----------------
template <bool A_BF16, bool C_BF16, bool C_TRANS>
__global__ __launch_bounds__(256) void gemm_bt(const void* __restrict__ Av,
                                               const u16* __restrict__ BT,
                                               const float* __restrict__ bias,
                                               void* __restrict__ Cv, int M) {
  constexpr int K = 1024, TM = 128, BK = 32;
  __shared__ u16 sA[TM * BK];
  __shared__ u16 sB[TM * BK];
  const int t = threadIdx.x;
  const int lane = t & 63;
  const int w = t >> 6;
  const int wr = w >> 1, wc = w & 1;
  // XCD-aware bijective tile swizzle (nwg % 8 == 0 for all our grids)
  int nwg = gridDim.x * gridDim.y;
  int lin = blockIdx.x + gridDim.x * blockIdx.y;
  int tile = lin;
  if ((nwg & 7) == 0) { int q = nwg >> 3; tile = (lin & 7) * q + (lin >> 3); }
  const int bx = tile % gridDim.x, by = tile / gridDim.x;
  const int m0 = bx * TM;
  const int n0 = by * TM;
  const int c16 = lane & 15, r16 = lane >> 4;

  f32x4_t acc[4][4] = {};

  for (int k0 = 0; k0 < K; k0 += BK) {
    if constexpr (A_BF16) {
      const u16* A = (const u16*)Av;
#pragma unroll
      for (int i = 0; i < 2; ++i) {
        int c = i * 256 + t;
        int row = c >> 2, ch = c & 3;
        async_load16(A + (size_t)(m0 + row) * K + k0 + ch * 8,
                     (char*)sA + (i * 256 + w * 64) * 16);
      }
    } else {
      const float* A = (const float*)Av;
#pragma unroll
      for (int i = 0; i < 4; ++i) {
        int c = i * 256 + t;
        int row = c >> 3, ch = c & 7;
        const float4 v = *(const float4*)(A + (size_t)(m0 + row) * K + k0 + ch * 4);
        ushort4 bv;
        bv.x = f2bf(v.x); bv.y = f2bf(v.y); bv.z = f2bf(v.z); bv.w = f2bf(v.w);
        *(ushort4*)&sA[row * BK + ch * 4] = bv;
      }
    }
#pragma unroll
    for (int i = 0; i < 2; ++i) {
      int c = i * 256 + t;
      int row = c >> 2, ch = c & 3;
      async_load16(BT + (size_t)(n0 + row) * K + k0 + ch * 8,
                   (char*)sB + (i * 256 + w * 64) * 16);
    }
    __syncthreads();

    bf16x8_t af[4], bfv[4];
#pragma unroll
    for (int m = 0; m < 4; ++m)
      af[m] = *(const bf16x8_t*)&sA[(wr * 64 + m * 16 + c16) * BK + r16 * 8];
#pragma unroll
    for (int n = 0; n < 4; ++n)
      bfv[n] = *(const bf16x8_t*)&sB[(wc * 64 + n * 16 + c16) * BK + r16 * 8];
#pragma unroll
    for (int m = 0; m < 4; ++m)
#pragma unroll
      for (int n = 0; n < 4; ++n)
        acc[m][n] = __builtin_amdgcn_mfma_f32_16x16x32_bf16(af[m], bfv[n], acc[m][n], 0, 0, 0);
    __syncthreads();
  }

#pragma unroll
  for (int m = 0; m < 4; ++m) {
    const int row0 = m0 + wr * 64 + m * 16 + r16 * 4;
#pragma unroll
    for (int n = 0; n < 4; ++n) {
      const int col = n0 + wc * 64 + n * 16 + c16;
      const float bvl = bias[col];
#pragma unroll
      for (int i = 0; i < 4; ++i) {
        const float val = acc[m][n][i] + bvl;
        if constexpr (C_TRANS)
          ((u16*)Cv)[(size_t)col * 256 + row0 + i] = f2bf(val);   // vd^T layout [1024][256]
        else if constexpr (C_BF16)
          ((u16*)Cv)[(size_t)(row0 + i) * 1024 + col] = f2bf(val);
        else
          ((float*)Cv)[(size_t)(row0 + i) * 1024 + col] = val;
      }
    }
  }
}

// ---------------- MFMA pooled attention ----------------
// qb: bf16 [B*4096][1024]; kdb: bf16 [256][1024] (rows b*64+k); vdTb: bf16 [1024][256]
// (rows n*64+d, cols b*64+k); av: bf16 [B*4096][1024]
__global__ __launch_bounds__(256) void attn_mfma(const u16* __restrict__ qb,
                                                 const u16* __restrict__ kdb,
                                                 const u16* __restrict__ vdTb,
                                                 u16* __restrict__ av) {
  __shared__ u16 sKD[64 * 64];
  __shared__ u16 sVD[64 * 64];
  __shared__ u16 sP[4][16 * 64];
  const int t = threadIdx.x;
  const int lane = t & 63;
  const int w = t >> 6;
  const int c16 = lane & 15;
  const int g = lane >> 4;
  const int stile = blockIdx.x, n = blockIdx.y, b = blockIdx.z;
  const int srow_base = b * 4096 + stile * 256 + w * 64;

  // q A-fragments straight from global (no intra-block reuse -> no staging)
  bf16x8_t aq[4][2];
#pragma unroll
  for (int st = 0; st < 4; ++st)
#pragma unroll
    for (int dt = 0; dt < 2; ++dt)
      aq[st][dt] = *(const bf16x8_t*)(qb + (size_t)(srow_base + st * 16 + c16) * 1024 +
                                      n * 64 + dt * 32 + g * 8);

  // stage kd tile [64 k][64 d] and vdT tile [64 d][64 k] with pre-swizzled source:
  // LDS holds data(row, cb) at row*128 + (cb ^ ((row&7)<<4))
#pragma unroll
  for (int c = 0; c < 2; ++c) {
    const int kk = c * 32 + (t >> 3);
    const int colb = ((t & 7) ^ (kk & 7)) << 4;
    async_load16((const char*)kdb + (size_t)(b * 64 + kk) * 2048 + n * 128 + colb,
                 (char*)sKD + c * 4096 + w * 1024);
  }
#pragma unroll
  for (int c = 0; c < 2; ++c) {
    const int dd = c * 32 + (t >> 3);
    const int colb = ((t & 7) ^ (dd & 7)) << 4;
    async_load16((const char*)vdTb + (size_t)(n * 64 + dd) * 512 + b * 128 + colb,
                 (char*)sVD + c * 4096 + w * 1024);
  }
  __syncthreads();

  const int swz = (c16 & 7) << 4;  // read-swizzle for rows ≡ c16 (mod 8)

  for (int st = 0; st < 4; ++st) {
    // ---- QK^T: scores[16 s][64 k] ----
    f32x4_t accs[4];
#pragma unroll
    for (int nn = 0; nn < 4; ++nn) {
      const u16* kr = &sKD[(nn * 16 + c16) * 64];
      bf16x8_t b0 = *(const bf16x8_t*)&kr[((g * 16) ^ swz) >> 1];
      bf16x8_t b1 = *(const bf16x8_t*)&kr[((64 + g * 16) ^ swz) >> 1];
      f32x4_t a = {0.f, 0.f, 0.f, 0.f};
      a = __builtin_amdgcn_mfma_f32_16x16x32_bf16(aq[st][0], b0, a, 0, 0, 0);
      a = __builtin_amdgcn_mfma_f32_16x16x32_bf16(aq[st][1], b1, a, 0, 0, 0);
      accs[nn] = a;
    }
    // ---- softmax over k (4 regs x 16 lanes per row) ----
    float ex[4][4], rs[4];
#pragma unroll
    for (int i = 0; i < 4; ++i) {
      float m = fmaxf(fmaxf(accs[0][i], accs[1][i]), fmaxf(accs[2][i], accs[3][i]));
#pragma unroll
      for (int off = 1; off < 16; off <<= 1) m = fmaxf(m, __shfl_xor(m, off));
      m *= 0.125f;
      float s = 0.f;
#pragma unroll
      for (int nn = 0; nn < 4; ++nn) {
        float e = __expf(accs[nn][i] * 0.125f - m);
        ex[nn][i] = e;
        s += e;
      }
#pragma unroll
      for (int off = 1; off < 16; off <<= 1) s += __shfl_xor(s, off);
      rs[i] = 1.f / s;
    }
    // ---- P -> LDS (swizzled [16][64]) for A-fragment reads ----
#pragma unroll
    for (int i = 0; i < 4; ++i) {
      const int row = g * 4 + i;
      const int rsw = (row & 7) << 4;
#pragma unroll
      for (int nn = 0; nn < 4; ++nn)
        sP[w][row * 64 + (((nn * 32 + c16 * 2) ^ rsw) >> 1)] = f2bf(ex[nn][i]);
    }
    bf16x8_t pa0 = *(const bf16x8_t*)&sP[w][c16 * 64 + (((g * 16) ^ swz) >> 1)];
    bf16x8_t pa1 = *(const bf16x8_t*)&sP[w][c16 * 64 + (((64 + g * 16) ^ swz) >> 1)];
    // ---- PV: av[16 s][64 d] ----
    f32x4_t accv[4];
#pragma unroll
    for (int dt = 0; dt < 4; ++dt) {
      const u16* vr = &sVD[(dt * 16 + c16) * 64];
      bf16x8_t v0 = *(const bf16x8_t*)&vr[((g * 16) ^ swz) >> 1];
      bf16x8_t v1 = *(const bf16x8_t*)&vr[((64 + g * 16) ^ swz) >> 1];
      f32x4_t a = {0.f, 0.f, 0.f, 0.f};
      a = __builtin_amdgcn_mfma_f32_16x16x32_bf16(pa0, v0, a, 0, 0, 0);
      a = __builtin_amdgcn_mfma_f32_16x16x32_bf16(pa1, v1, a, 0, 0, 0);
      accv[dt] = a;
    }
    // ---- normalize, stash in LDS (reuse sP), coalesced 16B global stores ----
#pragma unroll
    for (int i = 0; i < 4; ++i) {
      const int row = g * 4 + i;
      const int rsw = (row & 7) << 4;
#pragma unroll
      for (int dt = 0; dt < 4; ++dt)
        sP[w][row * 64 + (((dt * 32 + c16 * 2) ^ rsw) >> 1)] = f2bf(accv[dt][i] * rs[i]);
    }
#pragma unroll
    for (int r = 0; r < 2; ++r) {
      const int row = r * 8 + (lane >> 3);
      const int cb = ((lane & 7) * 16) ^ ((row & 7) << 4);
      bf16x8_t vv = *(const bf16x8_t*)&sP[w][row * 64 + (cb >> 1)];
      *(bf16x8_t*)(av + (size_t)(srow_base + st * 16 + row) * 1024 + n * 64 + (lane & 7) * 8) = vv;
    }
  }
}

extern "C" void kernel_launch(void* const* d_in, const int* in_sizes, int n_in,
                              void* d_out, int out_size, void* d_ws, size_t ws_size,
                              hipStream_t stream) {
  (void)in_sizes; (void)n_in; (void)out_size; (void)ws_size;
  const float* query = (const float*)d_in[0];
  const float* key   = (const float*)d_in[1];
  const float* value = (const float*)d_in[2];
  const float* Wq = (const float*)d_in[3];
  const float* bq = (const float*)d_in[4];
  const float* Wk = (const float*)d_in[5];
  const float* bk = (const float*)d_in[6];
  const float* Wv = (const float*)d_in[7];
  const float* bv = (const float*)d_in[8];
  const float* Wo = (const float*)d_in[9];
  const float* bo = (const float*)d_in[10];
  float* out = (float*)d_out;

  char* ws = (char*)d_ws;
  const size_t MB = 1024 * 1024;
  u16* WqT    = (u16*)(ws + 0 * MB);              // 2MB bf16 [nd][h]
  u16* WkT    = (u16*)(ws + 2 * MB);              // 2MB
  u16* WvT    = (u16*)(ws + 4 * MB);              // 2MB
  u16* WoT    = (u16*)(ws + 6 * MB);              // 2MB bf16 [h][nd]
  u16* keyd   = (u16*)(ws + 8 * MB);              // 0.5MB bf16 [256][1024]
  u16* valued = (u16*)(ws + 8 * MB + 512 * 1024); // 0.5MB
  u16* kdb    = (u16*)(ws + 9 * MB);              // 0.5MB bf16 [256][1024]
  u16* vdTb   = (u16*)(ws + 9 * MB + 512 * 1024); // 0.5MB bf16 [1024][256]
  u16* avb    = (u16*)(ws + 10 * MB);             // 32MB bf16 [16384][1024]
  u16* qbuf   = (u16*)d_out;                      // 32MB scratch inside 64MB d_out

  dim3 blk(256);

  // 1) weight transposes (one fused launch)
  transpose_w4<<<dim3(16, 16, 4), blk, 0, stream>>>(Wq, Wk, Wv, Wo, WqT, WkT, WvT, WoT);

  // 2) downsample key/value BEFORE projection (mean commutes with linear proj)
  downsample2<<<dim3(256, 4, 2), blk, 0, stream>>>(key, value, keyd, valued);

  // 3) kd = keyd @ Wk + bk (bf16) ; vdT = (valued @ Wv + bv)^T (bf16)
  gemm_bt<true, true, false><<<dim3(2, 8), blk, 0, stream>>>(keyd, WkT, bk, kdb, 256);
  gemm_bt<true, true, true><<<dim3(2, 8), blk, 0, stream>>>(valued, WvT, bv, vdTb, 256);

  // 4) q = query @ Wq + bq  (bf16 out, stashed in d_out)
  gemm_bt<false, true, false><<<dim3(128, 8), blk, 0, stream>>>(query, WqT, bq, qbuf, 16384);

  // 5) MFMA pooled attention -> a_v (bf16)
  attn_mfma<<<dim3(16, 16, 4), blk, 0, stream>>>(qbuf, kdb, vdTb, avb);

  // 6) out = a_v @ Wo + bo  (fp32 into d_out)
  gemm_bt<true, false, false><<<dim3(128, 8), blk, 0, stream>>>(avb, WoT, bo, out, 16384);
}

// Round 3
// 209.856 us; speedup vs baseline: 1.6729x; 1.2281x over previous
//
#include <hip/hip_runtime.h>

typedef unsigned short u16;
typedef unsigned int u32;
typedef __attribute__((ext_vector_type(8))) short bf16x8_t;
typedef __attribute__((ext_vector_type(4))) float f32x4_t;

// Problem constants: B=4, S=4096, H=1024, N=16, D=64, K-pool=64

__device__ __forceinline__ u16 f2bf(float f) {
  union { float f; u32 u; } a; a.f = f;
  u32 u = a.u;
  u32 r = (u + 0x7FFFu + ((u >> 16) & 1u)) >> 16;  // RNE
  return (u16)r;
}
__device__ __forceinline__ float bf2f(u16 x) {
  union { u32 u; float f; } a; a.u = ((u32)x) << 16; return a.f;
}

__device__ __forceinline__ void async_load16(const void* g, void* l) {
  __builtin_amdgcn_global_load_lds(
      (const __attribute__((address_space(1))) void*)g,
      (__attribute__((address_space(3))) void*)l, 16, 0, 0);
}

// ---------------- query fp32 -> bf16 (enables global_load_lds A-path in big GEMM) ----------------
__global__ __launch_bounds__(256) void cvt_bf16(const float* __restrict__ x,
                                                u16* __restrict__ y) {
  const size_t i = (size_t)(blockIdx.x * 256 + threadIdx.x) * 8;
  const float4 a = *(const float4*)(x + i);
  const float4 b = *(const float4*)(x + i + 4);
  bf16x8_t o;
  o[0] = (short)f2bf(a.x); o[1] = (short)f2bf(a.y);
  o[2] = (short)f2bf(a.z); o[3] = (short)f2bf(a.w);
  o[4] = (short)f2bf(b.x); o[5] = (short)f2bf(b.y);
  o[6] = (short)f2bf(b.z); o[7] = (short)f2bf(b.w);
  *(bf16x8_t*)(y + i) = o;
}

// ---------------- fused weight transposes: 4x W[1024][1024] fp32 -> WT bf16 ----------------
__global__ __launch_bounds__(256) void transpose_w4(const float* __restrict__ W0,
                                                    const float* __restrict__ W1,
                                                    const float* __restrict__ W2,
                                                    const float* __restrict__ W3,
                                                    u16* __restrict__ T0, u16* __restrict__ T1,
                                                    u16* __restrict__ T2, u16* __restrict__ T3) {
  const int z = blockIdx.z;
  const float* W = (z == 0) ? W0 : (z == 1) ? W1 : (z == 2) ? W2 : W3;
  u16* WT = (z == 0) ? T0 : (z == 1) ? T1 : (z == 2) ? T2 : T3;
  __shared__ float tile[64][65];
  const int tr = blockIdx.x * 64;
  const int tc = blockIdx.y * 64;
  const int t = threadIdx.x;
#pragma unroll
  for (int i = 0; i < 16; ++i) {
    int idx = i * 256 + t;
    int r = idx >> 6, c = idx & 63;
    tile[r][c] = W[(size_t)(tr + r) * 1024 + tc + c];
  }
  __syncthreads();
#pragma unroll
  for (int i = 0; i < 16; ++i) {
    int idx = i * 256 + t;
    int r = idx >> 6, c = idx & 63;
    WT[(size_t)(tc + r) * 1024 + tr + c] = f2bf(tile[c][r]);
  }
}

// ---------------- fused downsample: key,value [B,S,H] -> bf16 [B*64, H] ----------------
__global__ __launch_bounds__(256) void downsample2(const float* __restrict__ key,
                                                   const float* __restrict__ value,
                                                   u16* __restrict__ keyd,
                                                   u16* __restrict__ valued) {
  const float* x = blockIdx.z ? value : key;
  u16* xd = blockIdx.z ? valued : keyd;
  const int h = blockIdx.y * 256 + threadIdx.x;
  const int bkk = blockIdx.x;
  const float* p = x + (size_t)bkk * 65536 + h;
  float s = 0.f;
#pragma unroll
  for (int j = 0; j < 64; ++j) s += p[(size_t)j * 1024];
  xd[(size_t)bkk * 1024 + h] = f2bf(s * 0.015625f);
}

// ---------------- GEMM: C[M,1024] = A[M,1024](bf16) @ BT[1024,1024]^T + bias ----------------
// LDS layout: slot (row, c) holds data chunk (c ^ ((row>>1)&3)) of that row's 4x16B chunks
// (pre-swizzled global source for global_load_lds; same XOR on the ds_read side).
// BIG: grid is (128,8); rectangular XCD swizzle so each XCD owns 16 row-tiles x all 8
// N-panels (A-chunk 4MB + B 2MB, both L2-resident -> A fetched ~once from HBM).
template <bool C_BF16, bool C_TRANS, bool BIG>
__global__ __launch_bounds__(256) void gemm_bt(const u16* __restrict__ A,
                                               const u16* __restrict__ BT,
                                               const float* __restrict__ bias,
                                               void* __restrict__ Cv) {
  constexpr int K = 1024, TM = 128, BK = 32;
  __shared__ u16 sA[TM * BK];
  __shared__ u16 sB[TM * BK];
  const int t = threadIdx.x;
  const int lane = t & 63;
  const int w = t >> 6;
  const int wr = w >> 1, wc = w & 1;
  int bx, by;
  if constexpr (BIG) {
    const int lin = blockIdx.y * gridDim.x + blockIdx.x;  // dispatch order, %8 = XCD
    const int xcd = lin & 7, c = lin >> 3;                // c in [0,128)
    bx = xcd * 16 + (c >> 3);                             // 16 row-tiles per XCD
    by = c & 7;                                           // panel-fastest for A-reuse
  } else {
    bx = blockIdx.x; by = blockIdx.y;
  }
  const int m0 = bx * TM;
  const int n0 = by * TM;
  const int c16 = lane & 15, r16 = lane >> 4;

  f32x4_t acc[4][4] = {};

  for (int k0 = 0; k0 < K; k0 += BK) {
#pragma unroll
    for (int i = 0; i < 2; ++i) {
      const int idx = i * 256 + t;
      const int row = idx >> 2, ch = idx & 3;
      const int gch = ch ^ ((row >> 1) & 3);  // pre-swizzled source
      async_load16(A + (size_t)(m0 + row) * K + k0 + gch * 8,
                   (char*)sA + (i * 256 + w * 64) * 16);
    }
#pragma unroll
    for (int i = 0; i < 2; ++i) {
      const int idx = i * 256 + t;
      const int row = idx >> 2, ch = idx & 3;
      const int gch = ch ^ ((row >> 1) & 3);
      async_load16(BT + (size_t)(n0 + row) * K + k0 + gch * 8,
                   (char*)sB + (i * 256 + w * 64) * 16);
    }
    __syncthreads();

    bf16x8_t af[4], bfv[4];
#pragma unroll
    for (int m = 0; m < 4; ++m) {
      const int ra = wr * 64 + m * 16 + c16;
      af[m] = *(const bf16x8_t*)&sA[ra * BK + ((r16 ^ ((ra >> 1) & 3)) << 3)];
    }
#pragma unroll
    for (int n = 0; n < 4; ++n) {
      const int rb = wc * 64 + n * 16 + c16;
      bfv[n] = *(const bf16x8_t*)&sB[rb * BK + ((r16 ^ ((rb >> 1) & 3)) << 3)];
    }
#pragma unroll
    for (int m = 0; m < 4; ++m)
#pragma unroll
      for (int n = 0; n < 4; ++n)
        acc[m][n] = __builtin_amdgcn_mfma_f32_16x16x32_bf16(af[m], bfv[n], acc[m][n], 0, 0, 0);
    __syncthreads();
  }

#pragma unroll
  for (int m = 0; m < 4; ++m) {
    const int row0 = m0 + wr * 64 + m * 16 + r16 * 4;
#pragma unroll
    for (int n = 0; n < 4; ++n) {
      const int col = n0 + wc * 64 + n * 16 + c16;
      const float bvl = bias[col];
#pragma unroll
      for (int i = 0; i < 4; ++i) {
        const float val = acc[m][n][i] + bvl;
        if constexpr (C_TRANS)
          ((u16*)Cv)[(size_t)col * 256 + row0 + i] = f2bf(val);   // vd^T layout [1024][256]
        else if constexpr (C_BF16)
          ((u16*)Cv)[(size_t)(row0 + i) * 1024 + col] = f2bf(val);
        else
          ((float*)Cv)[(size_t)(row0 + i) * 1024 + col] = val;
      }
    }
  }
}

// ---------------- MFMA pooled attention ----------------
// qb: bf16 [B*4096][1024]; kdb: bf16 [256][1024] (rows b*64+k); vdTb: bf16 [1024][256]
// (rows n*64+d, cols b*64+k); av: bf16 [B*4096][1024]
__global__ __launch_bounds__(256) void attn_mfma(const u16* __restrict__ qb,
                                                 const u16* __restrict__ kdb,
                                                 const u16* __restrict__ vdTb,
                                                 u16* __restrict__ av) {
  __shared__ u16 sKD[64 * 64];
  __shared__ u16 sVD[64 * 64];
  __shared__ u16 sP[4][16 * 64];
  const int t = threadIdx.x;
  const int lane = t & 63;
  const int w = t >> 6;
  const int c16 = lane & 15;
  const int g = lane >> 4;
  const int stile = blockIdx.x, n = blockIdx.y, b = blockIdx.z;
  const int srow_base = b * 4096 + stile * 256 + w * 64;

  // q A-fragments straight from global (no intra-block reuse -> no staging)
  bf16x8_t aq[4][2];
#pragma unroll
  for (int st = 0; st < 4; ++st)
#pragma unroll
    for (int dt = 0; dt < 2; ++dt)
      aq[st][dt] = *(const bf16x8_t*)(qb + (size_t)(srow_base + st * 16 + c16) * 1024 +
                                      n * 64 + dt * 32 + g * 8);

  // stage kd tile [64 k][64 d] and vdT tile [64 d][64 k] with pre-swizzled source:
  // LDS holds data(row, cb) at row*128 + (cb ^ ((row&7)<<4))
#pragma unroll
  for (int c = 0; c < 2; ++c) {
    const int kk = c * 32 + (t >> 3);
    const int colb = ((t & 7) ^ (kk & 7)) << 4;
    async_load16((const char*)kdb + (size_t)(b * 64 + kk) * 2048 + n * 128 + colb,
                 (char*)sKD + c * 4096 + w * 1024);
  }
#pragma unroll
  for (int c = 0; c < 2; ++c) {
    const int dd = c * 32 + (t >> 3);
    const int colb = ((t & 7) ^ (dd & 7)) << 4;
    async_load16((const char*)vdTb + (size_t)(n * 64 + dd) * 512 + b * 128 + colb,
                 (char*)sVD + c * 4096 + w * 1024);
  }
  __syncthreads();

  const int swz = (c16 & 7) << 4;  // read-swizzle for rows ≡ c16 (mod 8)

  for (int st = 0; st < 4; ++st) {
    // ---- QK^T: scores[16 s][64 k] ----
    f32x4_t accs[4];
#pragma unroll
    for (int nn = 0; nn < 4; ++nn) {
      const u16* kr = &sKD[(nn * 16 + c16) * 64];
      bf16x8_t b0 = *(const bf16x8_t*)&kr[((g * 16) ^ swz) >> 1];
      bf16x8_t b1 = *(const bf16x8_t*)&kr[((64 + g * 16) ^ swz) >> 1];
      f32x4_t a = {0.f, 0.f, 0.f, 0.f};
      a = __builtin_amdgcn_mfma_f32_16x16x32_bf16(aq[st][0], b0, a, 0, 0, 0);
      a = __builtin_amdgcn_mfma_f32_16x16x32_bf16(aq[st][1], b1, a, 0, 0, 0);
      accs[nn] = a;
    }
    // ---- softmax over k (4 regs x 16 lanes per row) ----
    float ex[4][4], rs[4];
#pragma unroll
    for (int i = 0; i < 4; ++i) {
      float m = fmaxf(fmaxf(accs[0][i], accs[1][i]), fmaxf(accs[2][i], accs[3][i]));
#pragma unroll
      for (int off = 1; off < 16; off <<= 1) m = fmaxf(m, __shfl_xor(m, off));
      m *= 0.125f;
      float s = 0.f;
#pragma unroll
      for (int nn = 0; nn < 4; ++nn) {
        float e = __expf(accs[nn][i] * 0.125f - m);
        ex[nn][i] = e;
        s += e;
      }
#pragma unroll
      for (int off = 1; off < 16; off <<= 1) s += __shfl_xor(s, off);
      rs[i] = 1.f / s;
    }
    // ---- P -> LDS (swizzled [16][64]) for A-fragment reads ----
#pragma unroll
    for (int i = 0; i < 4; ++i) {
      const int row = g * 4 + i;
      const int rsw = (row & 7) << 4;
#pragma unroll
      for (int nn = 0; nn < 4; ++nn)
        sP[w][row * 64 + (((nn * 32 + c16 * 2) ^ rsw) >> 1)] = f2bf(ex[nn][i]);
    }
    bf16x8_t pa0 = *(const bf16x8_t*)&sP[w][c16 * 64 + (((g * 16) ^ swz) >> 1)];
    bf16x8_t pa1 = *(const bf16x8_t*)&sP[w][c16 * 64 + (((64 + g * 16) ^ swz) >> 1)];
    // ---- PV: av[16 s][64 d] ----
    f32x4_t accv[4];
#pragma unroll
    for (int dt = 0; dt < 4; ++dt) {
      const u16* vr = &sVD[(dt * 16 + c16) * 64];
      bf16x8_t v0 = *(const bf16x8_t*)&vr[((g * 16) ^ swz) >> 1];
      bf16x8_t v1 = *(const bf16x8_t*)&vr[((64 + g * 16) ^ swz) >> 1];
      f32x4_t a = {0.f, 0.f, 0.f, 0.f};
      a = __builtin_amdgcn_mfma_f32_16x16x32_bf16(pa0, v0, a, 0, 0, 0);
      a = __builtin_amdgcn_mfma_f32_16x16x32_bf16(pa1, v1, a, 0, 0, 0);
      accv[dt] = a;
    }
    // ---- normalize, stash in LDS (reuse sP), coalesced 16B global stores ----
#pragma unroll
    for (int i = 0; i < 4; ++i) {
      const int row = g * 4 + i;
      const int rsw = (row & 7) << 4;
#pragma unroll
      for (int dt = 0; dt < 4; ++dt)
        sP[w][row * 64 + (((dt * 32 + c16 * 2) ^ rsw) >> 1)] = f2bf(accv[dt][i] * rs[i]);
    }
#pragma unroll
    for (int r = 0; r < 2; ++r) {
      const int row = r * 8 + (lane >> 3);
      const int cb = ((lane & 7) * 16) ^ ((row & 7) << 4);
      bf16x8_t vv = *(const bf16x8_t*)&sP[w][row * 64 + (cb >> 1)];
      *(bf16x8_t*)(av + (size_t)(srow_base + st * 16 + row) * 1024 + n * 64 + (lane & 7) * 8) = vv;
    }
  }
}

extern "C" void kernel_launch(void* const* d_in, const int* in_sizes, int n_in,
                              void* d_out, int out_size, void* d_ws, size_t ws_size,
                              hipStream_t stream) {
  (void)in_sizes; (void)n_in; (void)out_size; (void)ws_size;
  const float* query = (const float*)d_in[0];
  const float* key   = (const float*)d_in[1];
  const float* value = (const float*)d_in[2];
  const float* Wq = (const float*)d_in[3];
  const float* bq = (const float*)d_in[4];
  const float* Wk = (const float*)d_in[5];
  const float* bk = (const float*)d_in[6];
  const float* Wv = (const float*)d_in[7];
  const float* bv = (const float*)d_in[8];
  const float* Wo = (const float*)d_in[9];
  const float* bo = (const float*)d_in[10];
  float* out = (float*)d_out;

  char* ws = (char*)d_ws;
  const size_t MB = 1024 * 1024;
  u16* WqT    = (u16*)(ws + 0 * MB);              // 2MB bf16 [nd][h]
  u16* WkT    = (u16*)(ws + 2 * MB);              // 2MB
  u16* WvT    = (u16*)(ws + 4 * MB);              // 2MB
  u16* WoT    = (u16*)(ws + 6 * MB);              // 2MB bf16 [h][nd]
  u16* keyd   = (u16*)(ws + 8 * MB);              // 0.5MB bf16 [256][1024]
  u16* valued = (u16*)(ws + 8 * MB + 512 * 1024); // 0.5MB
  u16* kdb    = (u16*)(ws + 9 * MB);              // 0.5MB bf16 [256][1024]
  u16* vdTb   = (u16*)(ws + 9 * MB + 512 * 1024); // 0.5MB bf16 [1024][256]
  u16* avb    = (u16*)(ws + 10 * MB);             // 32MB bf16 [16384][1024]
  u16* qbuf   = (u16*)d_out;                      // lo 32MB of d_out: projected q (bf16)
  u16* qcvt   = (u16*)((char*)d_out + 32 * MB);   // hi 32MB of d_out: query as bf16
  // (final fp32 out-GEMM overwrites all 64MB of d_out)

  dim3 blk(256);

  // 0) query fp32 -> bf16
  cvt_bf16<<<8192, blk, 0, stream>>>(query, qcvt);

  // 1) weight transposes (one fused launch)
  transpose_w4<<<dim3(16, 16, 4), blk, 0, stream>>>(Wq, Wk, Wv, Wo, WqT, WkT, WvT, WoT);

  // 2) downsample key/value BEFORE projection (mean commutes with linear proj)
  downsample2<<<dim3(256, 4, 2), blk, 0, stream>>>(key, value, keyd, valued);

  // 3) kd = keyd @ Wk + bk (bf16) ; vdT = (valued @ Wv + bv)^T (bf16)
  gemm_bt<true, false, false><<<dim3(2, 8), blk, 0, stream>>>(keyd, WkT, bk, kdb);
  gemm_bt<true, true, false><<<dim3(2, 8), blk, 0, stream>>>(valued, WvT, bv, vdTb);

  // 4) q = query @ Wq + bq  (bf16 out, stashed in d_out lo)
  gemm_bt<true, false, true><<<dim3(128, 8), blk, 0, stream>>>(qcvt, WqT, bq, qbuf);

  // 5) MFMA pooled attention -> a_v (bf16)
  attn_mfma<<<dim3(16, 16, 4), blk, 0, stream>>>(qbuf, kdb, vdTb, avb);

  // 6) out = a_v @ Wo + bo  (fp32 into d_out)
  gemm_bt<false, false, true><<<dim3(128, 8), blk, 0, stream>>>(avb, WoT, bo, out);
}

// Round 4
// 185.776 us; speedup vs baseline: 1.8898x; 1.1296x over previous
//
#include <hip/hip_runtime.h>

typedef unsigned short u16;
typedef unsigned int u32;
typedef __attribute__((ext_vector_type(8))) short bf16x8_t;
typedef __attribute__((ext_vector_type(4))) float f32x4_t;

// Problem constants: B=4, S=4096, H=1024, N=16, D=64, K-pool=64

#define MFMA_BF16 __builtin_amdgcn_mfma_f32_16x16x32_bf16

__device__ __forceinline__ u16 f2bf(float f) {
  union { float f; u32 u; } a; a.f = f;
  u32 u = a.u;
  u32 r = (u + 0x7FFFu + ((u >> 16) & 1u)) >> 16;  // RNE
  return (u16)r;
}
__device__ __forceinline__ float bf2f(u16 x) {
  union { u32 u; float f; } a; a.u = ((u32)x) << 16; return a.f;
}

__device__ __forceinline__ void async_load16(const void* g, void* l) {
  __builtin_amdgcn_global_load_lds(
      (const __attribute__((address_space(1))) void*)g,
      (__attribute__((address_space(3))) void*)l, 16, 0, 0);
}

// stage 64 rows x 128B (8KB, one issue/thread) with chunk pre-swizzle
// (LDS slot (row, c) holds global chunk c ^ (row&7); dest is linear).
__device__ __forceinline__ void stage64(const u16* __restrict__ src,
                                        char* lds_base, int t) {
  const int r = t >> 3;
  const int gch = (t & 7) ^ (r & 7);
  async_load16(src + (size_t)r * 1024 + gch * 8, lds_base + (t >> 6) * 1024);
}

// ---------------- query fp32 -> bf16 ----------------
__global__ __launch_bounds__(256) void cvt_bf16(const float* __restrict__ x,
                                                u16* __restrict__ y) {
  const size_t i = (size_t)(blockIdx.x * 256 + threadIdx.x) * 8;
  const float4 a = *(const float4*)(x + i);
  const float4 b = *(const float4*)(x + i + 4);
  bf16x8_t o;
  o[0] = (short)f2bf(a.x); o[1] = (short)f2bf(a.y);
  o[2] = (short)f2bf(a.z); o[3] = (short)f2bf(a.w);
  o[4] = (short)f2bf(b.x); o[5] = (short)f2bf(b.y);
  o[6] = (short)f2bf(b.z); o[7] = (short)f2bf(b.w);
  *(bf16x8_t*)(y + i) = o;
}

// ---------------- fused weight transposes: 4x W[1024][1024] fp32 -> WT bf16 ----------------
__global__ __launch_bounds__(256) void transpose_w4(const float* __restrict__ W0,
                                                    const float* __restrict__ W1,
                                                    const float* __restrict__ W2,
                                                    const float* __restrict__ W3,
                                                    u16* __restrict__ T0, u16* __restrict__ T1,
                                                    u16* __restrict__ T2, u16* __restrict__ T3) {
  const int z = blockIdx.z;
  const float* W = (z == 0) ? W0 : (z == 1) ? W1 : (z == 2) ? W2 : W3;
  u16* WT = (z == 0) ? T0 : (z == 1) ? T1 : (z == 2) ? T2 : T3;
  __shared__ float tile[64][65];
  const int tr = blockIdx.x * 64;
  const int tc = blockIdx.y * 64;
  const int t = threadIdx.x;
#pragma unroll
  for (int i = 0; i < 16; ++i) {
    int idx = i * 256 + t;
    int r = idx >> 6, c = idx & 63;
    tile[r][c] = W[(size_t)(tr + r) * 1024 + tc + c];
  }
  __syncthreads();
#pragma unroll
  for (int i = 0; i < 16; ++i) {
    int idx = i * 256 + t;
    int r = idx >> 6, c = idx & 63;
    WT[(size_t)(tc + r) * 1024 + tr + c] = f2bf(tile[c][r]);
  }
}

// ---------------- fused downsample: key,value [B,S,H] -> bf16 [B*64, H] ----------------
__global__ __launch_bounds__(256) void downsample2(const float* __restrict__ key,
                                                   const float* __restrict__ value,
                                                   u16* __restrict__ keyd,
                                                   u16* __restrict__ valued) {
  const float* x = blockIdx.z ? value : key;
  u16* xd = blockIdx.z ? valued : keyd;
  const int h = blockIdx.y * 256 + threadIdx.x;
  const int bkk = blockIdx.x;
  const float* p = x + (size_t)bkk * 65536 + h;
  float s = 0.f;
#pragma unroll
  for (int j = 0; j < 64; ++j) s += p[(size_t)j * 1024];
  xd[(size_t)bkk * 1024 + h] = f2bf(s * 0.015625f);
}

// ---------------- small GEMM (M=256): C = A @ BT^T + bias ----------------
template <bool C_BF16, bool C_TRANS>
__global__ __launch_bounds__(256) void gemm_bt(const u16* __restrict__ A,
                                               const u16* __restrict__ BT,
                                               const float* __restrict__ bias,
                                               void* __restrict__ Cv) {
  constexpr int K = 1024, BK = 32;
  __shared__ u16 sA[128 * BK];
  __shared__ u16 sB[128 * BK];
  const int t = threadIdx.x;
  const int lane = t & 63;
  const int w = t >> 6;
  const int wr = w >> 1, wc = w & 1;
  const int m0 = blockIdx.x * 128;
  const int n0 = blockIdx.y * 128;
  const int c16 = lane & 15, r16 = lane >> 4;

  f32x4_t acc[4][4] = {};

  for (int k0 = 0; k0 < K; k0 += BK) {
#pragma unroll
    for (int i = 0; i < 2; ++i) {
      const int idx = i * 256 + t;
      const int row = idx >> 2, ch = idx & 3;
      const int gch = ch ^ ((row >> 1) & 3);
      async_load16(A + (size_t)(m0 + row) * K + k0 + gch * 8,
                   (char*)sA + (i * 256 + w * 64) * 16);
    }
#pragma unroll
    for (int i = 0; i < 2; ++i) {
      const int idx = i * 256 + t;
      const int row = idx >> 2, ch = idx & 3;
      const int gch = ch ^ ((row >> 1) & 3);
      async_load16(BT + (size_t)(n0 + row) * K + k0 + gch * 8,
                   (char*)sB + (i * 256 + w * 64) * 16);
    }
    __syncthreads();

    bf16x8_t af[4], bfv[4];
#pragma unroll
    for (int m = 0; m < 4; ++m) {
      const int ra = wr * 64 + m * 16 + c16;
      af[m] = *(const bf16x8_t*)&sA[ra * BK + ((r16 ^ ((ra >> 1) & 3)) << 3)];
    }
#pragma unroll
    for (int n = 0; n < 4; ++n) {
      const int rb = wc * 64 + n * 16 + c16;
      bfv[n] = *(const bf16x8_t*)&sB[rb * BK + ((r16 ^ ((rb >> 1) & 3)) << 3)];
    }
#pragma unroll
    for (int m = 0; m < 4; ++m)
#pragma unroll
      for (int n = 0; n < 4; ++n)
        acc[m][n] = MFMA_BF16(af[m], bfv[n], acc[m][n], 0, 0, 0);
    __syncthreads();
  }

#pragma unroll
  for (int m = 0; m < 4; ++m) {
    const int row0 = m0 + wr * 64 + m * 16 + r16 * 4;
#pragma unroll
    for (int n = 0; n < 4; ++n) {
      const int col = n0 + wc * 64 + n * 16 + c16;
      const float bvl = bias[col];
#pragma unroll
      for (int i = 0; i < 4; ++i) {
        const float val = acc[m][n][i] + bvl;
        if constexpr (C_TRANS)
          ((u16*)Cv)[(size_t)col * 256 + row0 + i] = f2bf(val);
        else if constexpr (C_BF16)
          ((u16*)Cv)[(size_t)(row0 + i) * 1024 + col] = f2bf(val);
        else
          ((float*)Cv)[(size_t)(row0 + i) * 1024 + col] = val;
      }
    }
  }
}

// ---------------- 256x256 8-phase GEMM: C[16384,1024] = A @ BT^T + bias ----------------
// 512 thr = 8 waves (2M x 4N); per-wave out 128x64; BK=64; LDS 128KB double-buffered.
// Per-thread issue stream (2 global_load_lds per phase), block kt:
//   p0:[kt+1:A2,A3]  p1:[kt+2:A0,A1]  p2:[kt+2:B0,B1]  p3:[kt+2:B2,B3]
// Waits: end-p1 vmcnt(10) (forces [kt:A2,A3]); end-p3 vmcnt(8) (forces K-tile kt+1 fully).
// Every staged region's last ds_read completed before a barrier preceding the issue.
template <bool C_BF16>
__global__ __launch_bounds__(512) void gemm256(const u16* __restrict__ A,
                                               const u16* __restrict__ BT,
                                               const float* __restrict__ bias,
                                               void* __restrict__ Cv) {
  __shared__ u16 sAB[65536];  // 128 KB: [slot][A 32KB | B 32KB]
  char* lds = (char*)sAB;
  const int t = threadIdx.x;
  const int lane = t & 63;
  const int w = t >> 6;
  const int wm = w >> 2, wn = w & 3;
  const int c16 = lane & 15, r16 = lane >> 4, c7 = c16 & 7;

  // XCD swizzle: 256 blocks, XCD x owns bx in [x*8,(x+1)*8) x all 4 by panels
  const int tile = (blockIdx.x & 7) * 32 + (blockIdx.x >> 3);
  const int bx = tile >> 2, by = tile & 3;

  const u16* Ab = A + (size_t)bx * 256 * 1024;
  const u16* Bb = BT + (size_t)by * 256 * 1024;

  // prologue: K0 full (A0,A1,B0..B3,A2,A3) + K1 first 6 (A0,A1,B0..B3)
  stage64(Ab,                      lds,                   t);  // [0:A0] rows 0-63
  stage64(Ab + 128 * 1024,         lds + 128 * 128,       t);  // [0:A1] rows 128-191
  stage64(Bb,                      lds + 32768,           t);  // [0:B0]
  stage64(Bb + 64 * 1024,          lds + 32768 + 8192,    t);
  stage64(Bb + 128 * 1024,         lds + 32768 + 16384,   t);
  stage64(Bb + 192 * 1024,         lds + 32768 + 24576,   t);
  stage64(Ab + 64 * 1024,          lds + 64 * 128,        t);  // [0:A2] rows 64-127
  stage64(Ab + 192 * 1024,         lds + 192 * 128,       t);  // [0:A3] rows 192-255
  stage64(Ab + 64,                 lds + 65536,           t);  // [1:A0]
  stage64(Ab + 128 * 1024 + 64,    lds + 65536 + 16384,   t);  // [1:A1]
  stage64(Bb + 64,                 lds + 98304,           t);  // [1:B0]
  stage64(Bb + 64 * 1024 + 64,     lds + 98304 + 8192,    t);
  stage64(Bb + 128 * 1024 + 64,    lds + 98304 + 16384,   t);
  stage64(Bb + 192 * 1024 + 64,    lds + 98304 + 24576,   t);
  asm volatile("s_waitcnt vmcnt(6)" ::: "memory");  // K0 complete; K1's 6 in flight
  __builtin_amdgcn_s_barrier();

  f32x4_t acc[8][4] = {};
  bf16x8_t bf[4][2];

  for (int kt = 0; kt < 16; ++kt) {
    const int slot = kt & 1;
    const u16* sAs = (const u16*)(lds + slot * 65536);
    const u16* sBs = (const u16*)(lds + slot * 65536 + 32768);
    char* sAn = lds + (slot ^ 1) * 65536;
    char* sAc = lds + slot * 65536;
    char* sBc = lds + slot * 65536 + 32768;
    const int k1 = (kt < 15 ? kt + 1 : 15) * 64;  // clamp keeps vmcnt counts uniform;
    const int k2 = (kt < 14 ? kt + 2 : 15) * 64;  // clamped writes land in dead regions

    bf16x8_t af[4][2];
    // ---------------- phase 0: quadrant (m0-3, n0-1) ----------------
#pragma unroll
    for (int m = 0; m < 4; ++m) {
      const int row = wm * 128 + m * 16 + c16;
#pragma unroll
      for (int kk = 0; kk < 2; ++kk)
        af[m][kk] = *(const bf16x8_t*)&sAs[row * 64 + (((kk * 4 + r16) ^ c7) << 3)];
    }
#pragma unroll
    for (int n = 0; n < 2; ++n) {
      const int row = wn * 64 + n * 16 + c16;
#pragma unroll
      for (int kk = 0; kk < 2; ++kk)
        bf[n][kk] = *(const bf16x8_t*)&sBs[row * 64 + (((kk * 4 + r16) ^ c7) << 3)];
    }
    stage64(Ab + (size_t)64 * 1024 + k1,  sAn + 64 * 128,  t);   // [kt+1:A2]
    stage64(Ab + (size_t)192 * 1024 + k1, sAn + 192 * 128, t);   // [kt+1:A3]
    asm volatile("" ::: "memory");
    __builtin_amdgcn_s_barrier();
    asm volatile("s_waitcnt lgkmcnt(0)" ::: "memory");
    __builtin_amdgcn_sched_barrier(0);
    __builtin_amdgcn_s_setprio(1);
#pragma unroll
    for (int m = 0; m < 4; ++m)
#pragma unroll
      for (int n = 0; n < 2; ++n)
#pragma unroll
        for (int kk = 0; kk < 2; ++kk)
          acc[m][n] = MFMA_BF16(af[m][kk], bf[n][kk], acc[m][n], 0, 0, 0);
    __builtin_amdgcn_s_setprio(0);
    asm volatile("" ::: "memory");
    __builtin_amdgcn_s_barrier();
    // ---------------- phase 1: quadrant (m0-3, n2-3) ----------------
#pragma unroll
    for (int n = 2; n < 4; ++n) {
      const int row = wn * 64 + n * 16 + c16;
#pragma unroll
      for (int kk = 0; kk < 2; ++kk)
        bf[n][kk] = *(const bf16x8_t*)&sBs[row * 64 + (((kk * 4 + r16) ^ c7) << 3)];
    }
    stage64(Ab + k2,                      sAc,             t);   // [kt+2:A0]
    stage64(Ab + (size_t)128 * 1024 + k2, sAc + 128 * 128, t);   // [kt+2:A1]
    asm volatile("" ::: "memory");
    __builtin_amdgcn_s_barrier();
    asm volatile("s_waitcnt lgkmcnt(0)" ::: "memory");
    __builtin_amdgcn_sched_barrier(0);
    __builtin_amdgcn_s_setprio(1);
#pragma unroll
    for (int m = 0; m < 4; ++m)
#pragma unroll
      for (int n = 2; n < 4; ++n)
#pragma unroll
        for (int kk = 0; kk < 2; ++kk)
          acc[m][n] = MFMA_BF16(af[m][kk], bf[n][kk], acc[m][n], 0, 0, 0);
    __builtin_amdgcn_s_setprio(0);
    asm volatile("s_waitcnt vmcnt(10)" ::: "memory");  // forces [kt:A2,A3] done
    __builtin_amdgcn_s_barrier();
    // ---------------- phase 2: quadrant (m4-7, n0-1) ----------------
#pragma unroll
    for (int m = 0; m < 4; ++m) {
      const int row = wm * 128 + 64 + m * 16 + c16;
#pragma unroll
      for (int kk = 0; kk < 2; ++kk)
        af[m][kk] = *(const bf16x8_t*)&sAs[row * 64 + (((kk * 4 + r16) ^ c7) << 3)];
    }
    stage64(Bb + k2,                     sBc,           t);      // [kt+2:B0]
    stage64(Bb + (size_t)64 * 1024 + k2, sBc + 8192,    t);      // [kt+2:B1]
    asm volatile("" ::: "memory");
    __builtin_amdgcn_s_barrier();
    asm volatile("s_waitcnt lgkmcnt(0)" ::: "memory");
    __builtin_amdgcn_sched_barrier(0);
    __builtin_amdgcn_s_setprio(1);
#pragma unroll
    for (int m = 0; m < 4; ++m)
#pragma unroll
      for (int n = 0; n < 2; ++n)
#pragma unroll
        for (int kk = 0; kk < 2; ++kk)
          acc[4 + m][n] = MFMA_BF16(af[m][kk], bf[n][kk], acc[4 + m][n], 0, 0, 0);
    __builtin_amdgcn_s_setprio(0);
    asm volatile("" ::: "memory");
    __builtin_amdgcn_s_barrier();
    // ---------------- phase 3: quadrant (m4-7, n2-3) ----------------
    stage64(Bb + (size_t)128 * 1024 + k2, sBc + 16384, t);       // [kt+2:B2]
    stage64(Bb + (size_t)192 * 1024 + k2, sBc + 24576, t);       // [kt+2:B3]
    asm volatile("" ::: "memory");
    __builtin_amdgcn_s_barrier();
    __builtin_amdgcn_sched_barrier(0);
    __builtin_amdgcn_s_setprio(1);
#pragma unroll
    for (int m = 0; m < 4; ++m)
#pragma unroll
      for (int n = 2; n < 4; ++n)
#pragma unroll
        for (int kk = 0; kk < 2; ++kk)
          acc[4 + m][n] = MFMA_BF16(af[m][kk], bf[n][kk], acc[4 + m][n], 0, 0, 0);
    __builtin_amdgcn_s_setprio(0);
    asm volatile("s_waitcnt vmcnt(8)" ::: "memory");  // forces K-tile kt+1 staged
    __builtin_amdgcn_s_barrier();
  }

  // epilogue
#pragma unroll
  for (int m = 0; m < 8; ++m) {
    const int grow = bx * 256 + wm * 128 + m * 16 + r16 * 4;
#pragma unroll
    for (int n = 0; n < 4; ++n) {
      const int col = by * 256 + wn * 64 + n * 16 + c16;
      const float bvl = bias[col];
#pragma unroll
      for (int i = 0; i < 4; ++i) {
        const float val = acc[m][n][i] + bvl;
        if constexpr (C_BF16)
          ((u16*)Cv)[(size_t)(grow + i) * 1024 + col] = f2bf(val);
        else
          ((float*)Cv)[(size_t)(grow + i) * 1024 + col] = val;
      }
    }
  }
}

// ---------------- MFMA pooled attention ----------------
__global__ __launch_bounds__(256) void attn_mfma(const u16* __restrict__ qb,
                                                 const u16* __restrict__ kdb,
                                                 const u16* __restrict__ vdTb,
                                                 u16* __restrict__ av) {
  __shared__ u16 sKD[64 * 64];
  __shared__ u16 sVD[64 * 64];
  __shared__ u16 sP[4][16 * 64];
  const int t = threadIdx.x;
  const int lane = t & 63;
  const int w = t >> 6;
  const int c16 = lane & 15;
  const int g = lane >> 4;
  const int stile = blockIdx.x, n = blockIdx.y, b = blockIdx.z;
  const int srow_base = b * 4096 + stile * 256 + w * 64;

  bf16x8_t aq[4][2];
#pragma unroll
  for (int st = 0; st < 4; ++st)
#pragma unroll
    for (int dt = 0; dt < 2; ++dt)
      aq[st][dt] = *(const bf16x8_t*)(qb + (size_t)(srow_base + st * 16 + c16) * 1024 +
                                      n * 64 + dt * 32 + g * 8);

#pragma unroll
  for (int c = 0; c < 2; ++c) {
    const int kk = c * 32 + (t >> 3);
    const int colb = ((t & 7) ^ (kk & 7)) << 4;
    async_load16((const char*)kdb + (size_t)(b * 64 + kk) * 2048 + n * 128 + colb,
                 (char*)sKD + c * 4096 + w * 1024);
  }
#pragma unroll
  for (int c = 0; c < 2; ++c) {
    const int dd = c * 32 + (t >> 3);
    const int colb = ((t & 7) ^ (dd & 7)) << 4;
    async_load16((const char*)vdTb + (size_t)(n * 64 + dd) * 512 + b * 128 + colb,
                 (char*)sVD + c * 4096 + w * 1024);
  }
  __syncthreads();

  const int swz = (c16 & 7) << 4;

  for (int st = 0; st < 4; ++st) {
    f32x4_t accs[4];
#pragma unroll
    for (int nn = 0; nn < 4; ++nn) {
      const u16* kr = &sKD[(nn * 16 + c16) * 64];
      bf16x8_t b0 = *(const bf16x8_t*)&kr[((g * 16) ^ swz) >> 1];
      bf16x8_t b1 = *(const bf16x8_t*)&kr[((64 + g * 16) ^ swz) >> 1];
      f32x4_t a = {0.f, 0.f, 0.f, 0.f};
      a = MFMA_BF16(aq[st][0], b0, a, 0, 0, 0);
      a = MFMA_BF16(aq[st][1], b1, a, 0, 0, 0);
      accs[nn] = a;
    }
    float ex[4][4], rs[4];
#pragma unroll
    for (int i = 0; i < 4; ++i) {
      float m = fmaxf(fmaxf(accs[0][i], accs[1][i]), fmaxf(accs[2][i], accs[3][i]));
#pragma unroll
      for (int off = 1; off < 16; off <<= 1) m = fmaxf(m, __shfl_xor(m, off));
      m *= 0.125f;
      float s = 0.f;
#pragma unroll
      for (int nn = 0; nn < 4; ++nn) {
        float e = __expf(accs[nn][i] * 0.125f - m);
        ex[nn][i] = e;
        s += e;
      }
#pragma unroll
      for (int off = 1; off < 16; off <<= 1) s += __shfl_xor(s, off);
      rs[i] = 1.f / s;
    }
#pragma unroll
    for (int i = 0; i < 4; ++i) {
      const int row = g * 4 + i;
      const int rsw = (row & 7) << 4;
#pragma unroll
      for (int nn = 0; nn < 4; ++nn)
        sP[w][row * 64 + (((nn * 32 + c16 * 2) ^ rsw) >> 1)] = f2bf(ex[nn][i]);
    }
    bf16x8_t pa0 = *(const bf16x8_t*)&sP[w][c16 * 64 + (((g * 16) ^ swz) >> 1)];
    bf16x8_t pa1 = *(const bf16x8_t*)&sP[w][c16 * 64 + (((64 + g * 16) ^ swz) >> 1)];
    f32x4_t accv[4];
#pragma unroll
    for (int dt = 0; dt < 4; ++dt) {
      const u16* vr = &sVD[(dt * 16 + c16) * 64];
      bf16x8_t v0 = *(const bf16x8_t*)&vr[((g * 16) ^ swz) >> 1];
      bf16x8_t v1 = *(const bf16x8_t*)&vr[((64 + g * 16) ^ swz) >> 1];
      f32x4_t a = {0.f, 0.f, 0.f, 0.f};
      a = MFMA_BF16(pa0, v0, a, 0, 0, 0);
      a = MFMA_BF16(pa1, v1, a, 0, 0, 0);
      accv[dt] = a;
    }
#pragma unroll
    for (int i = 0; i < 4; ++i) {
      const int row = g * 4 + i;
      const int rsw = (row & 7) << 4;
#pragma unroll
      for (int dt = 0; dt < 4; ++dt)
        sP[w][row * 64 + (((dt * 32 + c16 * 2) ^ rsw) >> 1)] = f2bf(accv[dt][i] * rs[i]);
    }
#pragma unroll
    for (int r = 0; r < 2; ++r) {
      const int row = r * 8 + (lane >> 3);
      const int cb = ((lane & 7) * 16) ^ ((row & 7) << 4);
      bf16x8_t vv = *(const bf16x8_t*)&sP[w][row * 64 + (cb >> 1)];
      *(bf16x8_t*)(av + (size_t)(srow_base + st * 16 + row) * 1024 + n * 64 + (lane & 7) * 8) = vv;
    }
  }
}

extern "C" void kernel_launch(void* const* d_in, const int* in_sizes, int n_in,
                              void* d_out, int out_size, void* d_ws, size_t ws_size,
                              hipStream_t stream) {
  (void)in_sizes; (void)n_in; (void)out_size; (void)ws_size;
  const float* query = (const float*)d_in[0];
  const float* key   = (const float*)d_in[1];
  const float* value = (const float*)d_in[2];
  const float* Wq = (const float*)d_in[3];
  const float* bq = (const float*)d_in[4];
  const float* Wk = (const float*)d_in[5];
  const float* bk = (const float*)d_in[6];
  const float* Wv = (const float*)d_in[7];
  const float* bv = (const float*)d_in[8];
  const float* Wo = (const float*)d_in[9];
  const float* bo = (const float*)d_in[10];
  float* out = (float*)d_out;

  char* ws = (char*)d_ws;
  const size_t MB = 1024 * 1024;
  u16* WqT    = (u16*)(ws + 0 * MB);
  u16* WkT    = (u16*)(ws + 2 * MB);
  u16* WvT    = (u16*)(ws + 4 * MB);
  u16* WoT    = (u16*)(ws + 6 * MB);
  u16* keyd   = (u16*)(ws + 8 * MB);
  u16* valued = (u16*)(ws + 8 * MB + 512 * 1024);
  u16* kdb    = (u16*)(ws + 9 * MB);
  u16* vdTb   = (u16*)(ws + 9 * MB + 512 * 1024);
  u16* avb    = (u16*)(ws + 10 * MB);             // 32MB bf16 [16384][1024]
  u16* qbuf   = (u16*)d_out;                      // lo 32MB of d_out
  u16* qcvt   = (u16*)((char*)d_out + 32 * MB);   // hi 32MB of d_out

  dim3 blk(256);

  cvt_bf16<<<8192, blk, 0, stream>>>(query, qcvt);
  transpose_w4<<<dim3(16, 16, 4), blk, 0, stream>>>(Wq, Wk, Wv, Wo, WqT, WkT, WvT, WoT);
  downsample2<<<dim3(256, 4, 2), blk, 0, stream>>>(key, value, keyd, valued);

  gemm_bt<true, false><<<dim3(2, 8), blk, 0, stream>>>(keyd, WkT, bk, kdb);
  gemm_bt<true, true><<<dim3(2, 8), blk, 0, stream>>>(valued, WvT, bv, vdTb);

  gemm256<true><<<256, 512, 0, stream>>>(qcvt, WqT, bq, qbuf);
  attn_mfma<<<dim3(16, 16, 4), blk, 0, stream>>>(qbuf, kdb, vdTb, avb);
  gemm256<false><<<256, 512, 0, stream>>>(avb, WoT, bo, out);
}

// Round 5
// 184.260 us; speedup vs baseline: 1.9053x; 1.0082x over previous
//
#include <hip/hip_runtime.h>

typedef unsigned short u16;
typedef unsigned int u32;
typedef __attribute__((ext_vector_type(8))) short bf16x8_t;
typedef __attribute__((ext_vector_type(4))) float f32x4_t;

// Problem constants: B=4, S=4096, H=1024, N=16, D=64, K-pool=64

#define MFMA_BF16 __builtin_amdgcn_mfma_f32_16x16x32_bf16

__device__ __forceinline__ u16 f2bf(float f) {
  union { float f; u32 u; } a; a.f = f;
  u32 u = a.u;
  u32 r = (u + 0x7FFFu + ((u >> 16) & 1u)) >> 16;  // RNE
  return (u16)r;
}
__device__ __forceinline__ float bf2f(u16 x) {
  union { u32 u; float f; } a; a.u = ((u32)x) << 16; return a.f;
}

__device__ __forceinline__ void async_load16(const void* g, void* l) {
  __builtin_amdgcn_global_load_lds(
      (const __attribute__((address_space(1))) void*)g,
      (__attribute__((address_space(3))) void*)l, 16, 0, 0);
}

// stage 64 rows x 128B (8KB, one issue/thread) with chunk pre-swizzle
// (LDS slot (row, c) holds global chunk c ^ (row&7); dest is linear).
__device__ __forceinline__ void stage64(const u16* __restrict__ src,
                                        char* lds_base, int t) {
  const int r = t >> 3;
  const int gch = (t & 7) ^ (r & 7);
  async_load16(src + (size_t)r * 1024 + gch * 8, lds_base + (t >> 6) * 1024);
}

// ---------------- query fp32 -> bf16 ----------------
__global__ __launch_bounds__(256) void cvt_bf16(const float* __restrict__ x,
                                                u16* __restrict__ y) {
  const size_t i = (size_t)(blockIdx.x * 256 + threadIdx.x) * 8;
  const float4 a = *(const float4*)(x + i);
  const float4 b = *(const float4*)(x + i + 4);
  bf16x8_t o;
  o[0] = (short)f2bf(a.x); o[1] = (short)f2bf(a.y);
  o[2] = (short)f2bf(a.z); o[3] = (short)f2bf(a.w);
  o[4] = (short)f2bf(b.x); o[5] = (short)f2bf(b.y);
  o[6] = (short)f2bf(b.z); o[7] = (short)f2bf(b.w);
  *(bf16x8_t*)(y + i) = o;
}

// ---------------- fused weight transposes: 4x W[1024][1024] fp32 -> WT bf16 ----------------
__global__ __launch_bounds__(256) void transpose_w4(const float* __restrict__ W0,
                                                    const float* __restrict__ W1,
                                                    const float* __restrict__ W2,
                                                    const float* __restrict__ W3,
                                                    u16* __restrict__ T0, u16* __restrict__ T1,
                                                    u16* __restrict__ T2, u16* __restrict__ T3) {
  const int z = blockIdx.z;
  const float* W = (z == 0) ? W0 : (z == 1) ? W1 : (z == 2) ? W2 : W3;
  u16* WT = (z == 0) ? T0 : (z == 1) ? T1 : (z == 2) ? T2 : T3;
  __shared__ float tile[64][65];
  const int tr = blockIdx.x * 64;
  const int tc = blockIdx.y * 64;
  const int t = threadIdx.x;
#pragma unroll
  for (int i = 0; i < 16; ++i) {
    int idx = i * 256 + t;
    int r = idx >> 6, c = idx & 63;
    tile[r][c] = W[(size_t)(tr + r) * 1024 + tc + c];
  }
  __syncthreads();
#pragma unroll
  for (int i = 0; i < 16; ++i) {
    int idx = i * 256 + t;
    int r = idx >> 6, c = idx & 63;
    WT[(size_t)(tc + r) * 1024 + tr + c] = f2bf(tile[c][r]);
  }
}

// ---------------- fused downsample: key,value [B,S,H] -> bf16 [B*64, H] ----------------
// float4 loads, 2-way row-split per block (512 thr), LDS combine, ushort4 store.
__global__ __launch_bounds__(512) void downsample2(const float* __restrict__ key,
                                                   const float* __restrict__ value,
                                                   u16* __restrict__ keyd,
                                                   u16* __restrict__ valued) {
  __shared__ float4 part[256];
  const float* x = blockIdx.y ? value : key;
  u16* xd = blockIdx.y ? valued : keyd;
  const int t = threadIdx.x;
  const int rg = t >> 8;   // row group 0/1 (32 rows each)
  const int ct = t & 255;  // float4-column index (covers 1024 cols)
  const int bkk = blockIdx.x;
  const float* p = x + (size_t)bkk * 65536 + (size_t)rg * 32 * 1024 + ct * 4;
  float4 s = {0.f, 0.f, 0.f, 0.f};
#pragma unroll
  for (int j = 0; j < 32; ++j) {
    const float4 v = *(const float4*)(p + (size_t)j * 1024);
    s.x += v.x; s.y += v.y; s.z += v.z; s.w += v.w;
  }
  if (rg) part[ct] = s;
  __syncthreads();
  if (!rg) {
    const float4 o = part[ct];
    ushort4 r;
    r.x = f2bf((s.x + o.x) * 0.015625f);
    r.y = f2bf((s.y + o.y) * 0.015625f);
    r.z = f2bf((s.z + o.z) * 0.015625f);
    r.w = f2bf((s.w + o.w) * 0.015625f);
    *(ushort4*)(xd + (size_t)bkk * 1024 + ct * 4) = r;
  }
}

// ---------------- small GEMM (M=256): C = A @ BT^T + bias ----------------
template <bool C_BF16, bool C_TRANS>
__global__ __launch_bounds__(256) void gemm_bt(const u16* __restrict__ A,
                                               const u16* __restrict__ BT,
                                               const float* __restrict__ bias,
                                               void* __restrict__ Cv) {
  constexpr int K = 1024, BK = 32;
  __shared__ u16 sA[128 * BK];
  __shared__ u16 sB[128 * BK];
  const int t = threadIdx.x;
  const int lane = t & 63;
  const int w = t >> 6;
  const int wr = w >> 1, wc = w & 1;
  const int m0 = blockIdx.x * 128;
  const int n0 = blockIdx.y * 128;
  const int c16 = lane & 15, r16 = lane >> 4;

  f32x4_t acc[4][4] = {};

  for (int k0 = 0; k0 < K; k0 += BK) {
#pragma unroll
    for (int i = 0; i < 2; ++i) {
      const int idx = i * 256 + t;
      const int row = idx >> 2, ch = idx & 3;
      const int gch = ch ^ ((row >> 1) & 3);
      async_load16(A + (size_t)(m0 + row) * K + k0 + gch * 8,
                   (char*)sA + (i * 256 + w * 64) * 16);
    }
#pragma unroll
    for (int i = 0; i < 2; ++i) {
      const int idx = i * 256 + t;
      const int row = idx >> 2, ch = idx & 3;
      const int gch = ch ^ ((row >> 1) & 3);
      async_load16(BT + (size_t)(n0 + row) * K + k0 + gch * 8,
                   (char*)sB + (i * 256 + w * 64) * 16);
    }
    __syncthreads();

    bf16x8_t af[4], bfv[4];
#pragma unroll
    for (int m = 0; m < 4; ++m) {
      const int ra = wr * 64 + m * 16 + c16;
      af[m] = *(const bf16x8_t*)&sA[ra * BK + ((r16 ^ ((ra >> 1) & 3)) << 3)];
    }
#pragma unroll
    for (int n = 0; n < 4; ++n) {
      const int rb = wc * 64 + n * 16 + c16;
      bfv[n] = *(const bf16x8_t*)&sB[rb * BK + ((r16 ^ ((rb >> 1) & 3)) << 3)];
    }
#pragma unroll
    for (int m = 0; m < 4; ++m)
#pragma unroll
      for (int n = 0; n < 4; ++n)
        acc[m][n] = MFMA_BF16(af[m], bfv[n], acc[m][n], 0, 0, 0);
    __syncthreads();
  }

#pragma unroll
  for (int m = 0; m < 4; ++m) {
    const int row0 = m0 + wr * 64 + m * 16 + r16 * 4;
#pragma unroll
    for (int n = 0; n < 4; ++n) {
      const int col = n0 + wc * 64 + n * 16 + c16;
      const float bvl = bias[col];
#pragma unroll
      for (int i = 0; i < 4; ++i) {
        const float val = acc[m][n][i] + bvl;
        if constexpr (C_TRANS)
          ((u16*)Cv)[(size_t)col * 256 + row0 + i] = f2bf(val);
        else if constexpr (C_BF16)
          ((u16*)Cv)[(size_t)(row0 + i) * 1024 + col] = f2bf(val);
        else
          ((float*)Cv)[(size_t)(row0 + i) * 1024 + col] = val;
      }
    }
  }
}

// ---------------- 256x256 8-phase GEMM: C[16384,1024] = A @ BT^T + bias ----------------
// 512 thr = 8 waves (2M x 4N); per-wave out 128x64; BK=64; LDS 128KB double-buffered.
// Per-thread issue stream (2 global_load_lds per phase), block kt:
//   p0:[kt+1:A2,A3]  p1:[kt+2:A0,A1]  p2:[kt+2:B0,B1]  p3:[kt+2:B2,B3]
// Waits: end-p1 vmcnt(10) (forces [kt:A2,A3]); end-p3 vmcnt(8) (forces K-tile kt+1 fully).
template <bool C_BF16>
__global__ __launch_bounds__(512) void gemm256(const u16* __restrict__ A,
                                               const u16* __restrict__ BT,
                                               const float* __restrict__ bias,
                                               void* __restrict__ Cv) {
  __shared__ u16 sAB[65536];  // 128 KB: [slot][A 32KB | B 32KB]
  char* lds = (char*)sAB;
  const int t = threadIdx.x;
  const int lane = t & 63;
  const int w = t >> 6;
  const int wm = w >> 2, wn = w & 3;
  const int c16 = lane & 15, r16 = lane >> 4, c7 = c16 & 7;

  // XCD swizzle: 256 blocks, XCD x owns bx in [x*8,(x+1)*8) x all 4 by panels
  const int tile = (blockIdx.x & 7) * 32 + (blockIdx.x >> 3);
  const int bx = tile >> 2, by = tile & 3;

  const u16* Ab = A + (size_t)bx * 256 * 1024;
  const u16* Bb = BT + (size_t)by * 256 * 1024;

  // prologue: K0 full (A0,A1,B0..B3,A2,A3) + K1 first 6 (A0,A1,B0..B3)
  stage64(Ab,                      lds,                   t);  // [0:A0] rows 0-63
  stage64(Ab + 128 * 1024,         lds + 128 * 128,       t);  // [0:A1] rows 128-191
  stage64(Bb,                      lds + 32768,           t);  // [0:B0]
  stage64(Bb + 64 * 1024,          lds + 32768 + 8192,    t);
  stage64(Bb + 128 * 1024,         lds + 32768 + 16384,   t);
  stage64(Bb + 192 * 1024,         lds + 32768 + 24576,   t);
  stage64(Ab + 64 * 1024,          lds + 64 * 128,        t);  // [0:A2] rows 64-127
  stage64(Ab + 192 * 1024,         lds + 192 * 128,       t);  // [0:A3] rows 192-255
  stage64(Ab + 64,                 lds + 65536,           t);  // [1:A0]
  stage64(Ab + 128 * 1024 + 64,    lds + 65536 + 16384,   t);  // [1:A1]
  stage64(Bb + 64,                 lds + 98304,           t);  // [1:B0]
  stage64(Bb + 64 * 1024 + 64,     lds + 98304 + 8192,    t);
  stage64(Bb + 128 * 1024 + 64,    lds + 98304 + 16384,   t);
  stage64(Bb + 192 * 1024 + 64,    lds + 98304 + 24576,   t);
  asm volatile("s_waitcnt vmcnt(6)" ::: "memory");  // K0 complete; K1's 6 in flight
  __builtin_amdgcn_s_barrier();

  f32x4_t acc[8][4] = {};
  bf16x8_t bf[4][2];

  for (int kt = 0; kt < 16; ++kt) {
    const int slot = kt & 1;
    const u16* sAs = (const u16*)(lds + slot * 65536);
    const u16* sBs = (const u16*)(lds + slot * 65536 + 32768);
    char* sAn = lds + (slot ^ 1) * 65536;
    char* sAc = lds + slot * 65536;
    char* sBc = lds + slot * 65536 + 32768;
    const int k1 = (kt < 15 ? kt + 1 : 15) * 64;  // clamp keeps vmcnt counts uniform;
    const int k2 = (kt < 14 ? kt + 2 : 15) * 64;  // clamped writes land in dead regions

    bf16x8_t af[4][2];
    // ---------------- phase 0: quadrant (m0-3, n0-1) ----------------
#pragma unroll
    for (int m = 0; m < 4; ++m) {
      const int row = wm * 128 + m * 16 + c16;
#pragma unroll
      for (int kk = 0; kk < 2; ++kk)
        af[m][kk] = *(const bf16x8_t*)&sAs[row * 64 + (((kk * 4 + r16) ^ c7) << 3)];
    }
#pragma unroll
    for (int n = 0; n < 2; ++n) {
      const int row = wn * 64 + n * 16 + c16;
#pragma unroll
      for (int kk = 0; kk < 2; ++kk)
        bf[n][kk] = *(const bf16x8_t*)&sBs[row * 64 + (((kk * 4 + r16) ^ c7) << 3)];
    }
    stage64(Ab + (size_t)64 * 1024 + k1,  sAn + 64 * 128,  t);   // [kt+1:A2]
    stage64(Ab + (size_t)192 * 1024 + k1, sAn + 192 * 128, t);   // [kt+1:A3]
    asm volatile("" ::: "memory");
    __builtin_amdgcn_s_barrier();
    asm volatile("s_waitcnt lgkmcnt(0)" ::: "memory");
    __builtin_amdgcn_sched_barrier(0);
    __builtin_amdgcn_s_setprio(1);
#pragma unroll
    for (int m = 0; m < 4; ++m)
#pragma unroll
      for (int n = 0; n < 2; ++n)
#pragma unroll
        for (int kk = 0; kk < 2; ++kk)
          acc[m][n] = MFMA_BF16(af[m][kk], bf[n][kk], acc[m][n], 0, 0, 0);
    __builtin_amdgcn_s_setprio(0);
    asm volatile("" ::: "memory");
    __builtin_amdgcn_s_barrier();
    // ---------------- phase 1: quadrant (m0-3, n2-3) ----------------
#pragma unroll
    for (int n = 2; n < 4; ++n) {
      const int row = wn * 64 + n * 16 + c16;
#pragma unroll
      for (int kk = 0; kk < 2; ++kk)
        bf[n][kk] = *(const bf16x8_t*)&sBs[row * 64 + (((kk * 4 + r16) ^ c7) << 3)];
    }
    stage64(Ab + k2,                      sAc,             t);   // [kt+2:A0]
    stage64(Ab + (size_t)128 * 1024 + k2, sAc + 128 * 128, t);   // [kt+2:A1]
    asm volatile("" ::: "memory");
    __builtin_amdgcn_s_barrier();
    asm volatile("s_waitcnt lgkmcnt(0)" ::: "memory");
    __builtin_amdgcn_sched_barrier(0);
    __builtin_amdgcn_s_setprio(1);
#pragma unroll
    for (int m = 0; m < 4; ++m)
#pragma unroll
      for (int n = 2; n < 4; ++n)
#pragma unroll
        for (int kk = 0; kk < 2; ++kk)
          acc[m][n] = MFMA_BF16(af[m][kk], bf[n][kk], acc[m][n], 0, 0, 0);
    __builtin_amdgcn_s_setprio(0);
    asm volatile("s_waitcnt vmcnt(10)" ::: "memory");  // forces [kt:A2,A3] done
    __builtin_amdgcn_s_barrier();
    // ---------------- phase 2: quadrant (m4-7, n0-1) ----------------
#pragma unroll
    for (int m = 0; m < 4; ++m) {
      const int row = wm * 128 + 64 + m * 16 + c16;
#pragma unroll
      for (int kk = 0; kk < 2; ++kk)
        af[m][kk] = *(const bf16x8_t*)&sAs[row * 64 + (((kk * 4 + r16) ^ c7) << 3)];
    }
    stage64(Bb + k2,                     sBc,           t);      // [kt+2:B0]
    stage64(Bb + (size_t)64 * 1024 + k2, sBc + 8192,    t);      // [kt+2:B1]
    asm volatile("" ::: "memory");
    __builtin_amdgcn_s_barrier();
    asm volatile("s_waitcnt lgkmcnt(0)" ::: "memory");
    __builtin_amdgcn_sched_barrier(0);
    __builtin_amdgcn_s_setprio(1);
#pragma unroll
    for (int m = 0; m < 4; ++m)
#pragma unroll
      for (int n = 0; n < 2; ++n)
#pragma unroll
        for (int kk = 0; kk < 2; ++kk)
          acc[4 + m][n] = MFMA_BF16(af[m][kk], bf[n][kk], acc[4 + m][n], 0, 0, 0);
    __builtin_amdgcn_s_setprio(0);
    asm volatile("" ::: "memory");
    __builtin_amdgcn_s_barrier();
    // ---------------- phase 3: quadrant (m4-7, n2-3) ----------------
    stage64(Bb + (size_t)128 * 1024 + k2, sBc + 16384, t);       // [kt+2:B2]
    stage64(Bb + (size_t)192 * 1024 + k2, sBc + 24576, t);       // [kt+2:B3]
    asm volatile("" ::: "memory");
    __builtin_amdgcn_s_barrier();
    __builtin_amdgcn_sched_barrier(0);
    __builtin_amdgcn_s_setprio(1);
#pragma unroll
    for (int m = 0; m < 4; ++m)
#pragma unroll
      for (int n = 2; n < 4; ++n)
#pragma unroll
        for (int kk = 0; kk < 2; ++kk)
          acc[4 + m][n] = MFMA_BF16(af[m][kk], bf[n][kk], acc[4 + m][n], 0, 0, 0);
    __builtin_amdgcn_s_setprio(0);
    asm volatile("s_waitcnt vmcnt(8)" ::: "memory");  // forces K-tile kt+1 staged
    __builtin_amdgcn_s_barrier();
  }

  // epilogue
#pragma unroll
  for (int m = 0; m < 8; ++m) {
    const int grow = bx * 256 + wm * 128 + m * 16 + r16 * 4;
#pragma unroll
    for (int n = 0; n < 4; ++n) {
      const int col = by * 256 + wn * 64 + n * 16 + c16;
      const float bvl = bias[col];
#pragma unroll
      for (int i = 0; i < 4; ++i) {
        const float val = acc[m][n][i] + bvl;
        if constexpr (C_BF16)
          ((u16*)Cv)[(size_t)(grow + i) * 1024 + col] = f2bf(val);
        else
          ((float*)Cv)[(size_t)(grow + i) * 1024 + col] = val;
      }
    }
  }
}

// ---------------- MFMA pooled attention ----------------
__global__ __launch_bounds__(256) void attn_mfma(const u16* __restrict__ qb,
                                                 const u16* __restrict__ kdb,
                                                 const u16* __restrict__ vdTb,
                                                 u16* __restrict__ av) {
  __shared__ u16 sKD[64 * 64];
  __shared__ u16 sVD[64 * 64];
  __shared__ u16 sP[4][16 * 64];
  const int t = threadIdx.x;
  const int lane = t & 63;
  const int w = t >> 6;
  const int c16 = lane & 15;
  const int g = lane >> 4;
  const int stile = blockIdx.x, n = blockIdx.y, b = blockIdx.z;
  const int srow_base = b * 4096 + stile * 256 + w * 64;

  bf16x8_t aq[4][2];
#pragma unroll
  for (int st = 0; st < 4; ++st)
#pragma unroll
    for (int dt = 0; dt < 2; ++dt)
      aq[st][dt] = *(const bf16x8_t*)(qb + (size_t)(srow_base + st * 16 + c16) * 1024 +
                                      n * 64 + dt * 32 + g * 8);

#pragma unroll
  for (int c = 0; c < 2; ++c) {
    const int kk = c * 32 + (t >> 3);
    const int colb = ((t & 7) ^ (kk & 7)) << 4;
    async_load16((const char*)kdb + (size_t)(b * 64 + kk) * 2048 + n * 128 + colb,
                 (char*)sKD + c * 4096 + w * 1024);
  }
#pragma unroll
  for (int c = 0; c < 2; ++c) {
    const int dd = c * 32 + (t >> 3);
    const int colb = ((t & 7) ^ (dd & 7)) << 4;
    async_load16((const char*)vdTb + (size_t)(n * 64 + dd) * 512 + b * 128 + colb,
                 (char*)sVD + c * 4096 + w * 1024);
  }
  __syncthreads();

  const int swz = (c16 & 7) << 4;

  for (int st = 0; st < 4; ++st) {
    f32x4_t accs[4];
#pragma unroll
    for (int nn = 0; nn < 4; ++nn) {
      const u16* kr = &sKD[(nn * 16 + c16) * 64];
      bf16x8_t b0 = *(const bf16x8_t*)&kr[((g * 16) ^ swz) >> 1];
      bf16x8_t b1 = *(const bf16x8_t*)&kr[((64 + g * 16) ^ swz) >> 1];
      f32x4_t a = {0.f, 0.f, 0.f, 0.f};
      a = MFMA_BF16(aq[st][0], b0, a, 0, 0, 0);
      a = MFMA_BF16(aq[st][1], b1, a, 0, 0, 0);
      accs[nn] = a;
    }
    float ex[4][4], rs[4];
#pragma unroll
    for (int i = 0; i < 4; ++i) {
      float m = fmaxf(fmaxf(accs[0][i], accs[1][i]), fmaxf(accs[2][i], accs[3][i]));
#pragma unroll
      for (int off = 1; off < 16; off <<= 1) m = fmaxf(m, __shfl_xor(m, off));
      m *= 0.125f;
      float s = 0.f;
#pragma unroll
      for (int nn = 0; nn < 4; ++nn) {
        float e = __expf(accs[nn][i] * 0.125f - m);
        ex[nn][i] = e;
        s += e;
      }
#pragma unroll
      for (int off = 1; off < 16; off <<= 1) s += __shfl_xor(s, off);
      rs[i] = 1.f / s;
    }
#pragma unroll
    for (int i = 0; i < 4; ++i) {
      const int row = g * 4 + i;
      const int rsw = (row & 7) << 4;
#pragma unroll
      for (int nn = 0; nn < 4; ++nn)
        sP[w][row * 64 + (((nn * 32 + c16 * 2) ^ rsw) >> 1)] = f2bf(ex[nn][i]);
    }
    bf16x8_t pa0 = *(const bf16x8_t*)&sP[w][c16 * 64 + (((g * 16) ^ swz) >> 1)];
    bf16x8_t pa1 = *(const bf16x8_t*)&sP[w][c16 * 64 + (((64 + g * 16) ^ swz) >> 1)];
    f32x4_t accv[4];
#pragma unroll
    for (int dt = 0; dt < 4; ++dt) {
      const u16* vr = &sVD[(dt * 16 + c16) * 64];
      bf16x8_t v0 = *(const bf16x8_t*)&vr[((g * 16) ^ swz) >> 1];
      bf16x8_t v1 = *(const bf16x8_t*)&vr[((64 + g * 16) ^ swz) >> 1];
      f32x4_t a = {0.f, 0.f, 0.f, 0.f};
      a = MFMA_BF16(pa0, v0, a, 0, 0, 0);
      a = MFMA_BF16(pa1, v1, a, 0, 0, 0);
      accv[dt] = a;
    }
#pragma unroll
    for (int i = 0; i < 4; ++i) {
      const int row = g * 4 + i;
      const int rsw = (row & 7) << 4;
#pragma unroll
      for (int dt = 0; dt < 4; ++dt)
        sP[w][row * 64 + (((dt * 32 + c16 * 2) ^ rsw) >> 1)] = f2bf(accv[dt][i] * rs[i]);
    }
#pragma unroll
    for (int r = 0; r < 2; ++r) {
      const int row = r * 8 + (lane >> 3);
      const int cb = ((lane & 7) * 16) ^ ((row & 7) << 4);
      bf16x8_t vv = *(const bf16x8_t*)&sP[w][row * 64 + (cb >> 1)];
      *(bf16x8_t*)(av + (size_t)(srow_base + st * 16 + row) * 1024 + n * 64 + (lane & 7) * 8) = vv;
    }
  }
}

extern "C" void kernel_launch(void* const* d_in, const int* in_sizes, int n_in,
                              void* d_out, int out_size, void* d_ws, size_t ws_size,
                              hipStream_t stream) {
  (void)in_sizes; (void)n_in; (void)out_size; (void)ws_size;
  const float* query = (const float*)d_in[0];
  const float* key   = (const float*)d_in[1];
  const float* value = (const float*)d_in[2];
  const float* Wq = (const float*)d_in[3];
  const float* bq = (const float*)d_in[4];
  const float* Wk = (const float*)d_in[5];
  const float* bk = (const float*)d_in[6];
  const float* Wv = (const float*)d_in[7];
  const float* bv = (const float*)d_in[8];
  const float* Wo = (const float*)d_in[9];
  const float* bo = (const float*)d_in[10];
  float* out = (float*)d_out;

  char* ws = (char*)d_ws;
  const size_t MB = 1024 * 1024;
  u16* WqT    = (u16*)(ws + 0 * MB);
  u16* WkT    = (u16*)(ws + 2 * MB);
  u16* WvT    = (u16*)(ws + 4 * MB);
  u16* WoT    = (u16*)(ws + 6 * MB);
  u16* keyd   = (u16*)(ws + 8 * MB);
  u16* valued = (u16*)(ws + 8 * MB + 512 * 1024);
  u16* kdb    = (u16*)(ws + 9 * MB);
  u16* vdTb   = (u16*)(ws + 9 * MB + 512 * 1024);
  u16* avb    = (u16*)(ws + 10 * MB);             // 32MB bf16 [16384][1024]
  u16* qbuf   = (u16*)d_out;                      // lo 32MB of d_out
  u16* qcvt   = (u16*)((char*)d_out + 32 * MB);   // hi 32MB of d_out

  dim3 blk(256);

  cvt_bf16<<<8192, blk, 0, stream>>>(query, qcvt);
  transpose_w4<<<dim3(16, 16, 4), blk, 0, stream>>>(Wq, Wk, Wv, Wo, WqT, WkT, WvT, WoT);
  downsample2<<<dim3(256, 2), 512, 0, stream>>>(key, value, keyd, valued);

  gemm_bt<true, false><<<dim3(2, 8), blk, 0, stream>>>(keyd, WkT, bk, kdb);
  gemm_bt<true, true><<<dim3(2, 8), blk, 0, stream>>>(valued, WvT, bv, vdTb);

  gemm256<true><<<256, 512, 0, stream>>>(qcvt, WqT, bq, qbuf);
  attn_mfma<<<dim3(16, 16, 4), blk, 0, stream>>>(qbuf, kdb, vdTb, avb);
  gemm256<false><<<256, 512, 0, stream>>>(avb, WoT, bo, out);
}

// Round 6
// 171.677 us; speedup vs baseline: 2.0450x; 1.0733x over previous
//
#include <hip/hip_runtime.h>

typedef unsigned short u16;
typedef unsigned int u32;
typedef __attribute__((ext_vector_type(8))) short bf16x8_t;
typedef __attribute__((ext_vector_type(4))) float f32x4_t;

// Problem constants: B=4, S=4096, H=1024, N=16, D=64, K-pool=64

#define MFMA_BF16 __builtin_amdgcn_mfma_f32_16x16x32_bf16

__device__ __forceinline__ u16 f2bf(float f) {
  union { float f; u32 u; } a; a.f = f;
  u32 u = a.u;
  u32 r = (u + 0x7FFFu + ((u >> 16) & 1u)) >> 16;  // RNE
  return (u16)r;
}
__device__ __forceinline__ float bf2f(u16 x) {
  union { u32 u; float f; } a; a.u = ((u32)x) << 16; return a.f;
}

__device__ __forceinline__ void async_load16(const void* g, void* l) {
  __builtin_amdgcn_global_load_lds(
      (const __attribute__((address_space(1))) void*)g,
      (__attribute__((address_space(3))) void*)l, 16, 0, 0);
}

// stage 64 rows x 128B (8KB, one issue/thread) with chunk pre-swizzle
// (LDS slot (row, c) holds global chunk c ^ (row&7); dest is linear).
__device__ __forceinline__ void stage64(const u16* __restrict__ src,
                                        char* lds_base, int t) {
  const int r = t >> 3;
  const int gch = (t & 7) ^ (r & 7);
  async_load16(src + (size_t)r * 1024 + gch * 8, lds_base + (t >> 6) * 1024);
}

// ---------------- query fp32 -> bf16 ----------------
__global__ __launch_bounds__(256) void cvt_bf16(const float* __restrict__ x,
                                                u16* __restrict__ y) {
  const size_t i = (size_t)(blockIdx.x * 256 + threadIdx.x) * 8;
  const float4 a = *(const float4*)(x + i);
  const float4 b = *(const float4*)(x + i + 4);
  bf16x8_t o;
  o[0] = (short)f2bf(a.x); o[1] = (short)f2bf(a.y);
  o[2] = (short)f2bf(a.z); o[3] = (short)f2bf(a.w);
  o[4] = (short)f2bf(b.x); o[5] = (short)f2bf(b.y);
  o[6] = (short)f2bf(b.z); o[7] = (short)f2bf(b.w);
  *(bf16x8_t*)(y + i) = o;
}

// ---------------- fused weight transposes: 4x W[1024][1024] fp32 -> WT bf16 ----------------
__global__ __launch_bounds__(256) void transpose_w4(const float* __restrict__ W0,
                                                    const float* __restrict__ W1,
                                                    const float* __restrict__ W2,
                                                    const float* __restrict__ W3,
                                                    u16* __restrict__ T0, u16* __restrict__ T1,
                                                    u16* __restrict__ T2, u16* __restrict__ T3) {
  const int z = blockIdx.z;
  const float* W = (z == 0) ? W0 : (z == 1) ? W1 : (z == 2) ? W2 : W3;
  u16* WT = (z == 0) ? T0 : (z == 1) ? T1 : (z == 2) ? T2 : T3;
  __shared__ float tile[64][65];
  const int tr = blockIdx.x * 64;
  const int tc = blockIdx.y * 64;
  const int t = threadIdx.x;
#pragma unroll
  for (int i = 0; i < 16; ++i) {
    int idx = i * 256 + t;
    int r = idx >> 6, c = idx & 63;
    tile[r][c] = W[(size_t)(tr + r) * 1024 + tc + c];
  }
  __syncthreads();
#pragma unroll
  for (int i = 0; i < 16; ++i) {
    int idx = i * 256 + t;
    int r = idx >> 6, c = idx & 63;
    WT[(size_t)(tc + r) * 1024 + tr + c] = f2bf(tile[c][r]);
  }
}

// ---------------- fused downsample: key,value [B,S,H] -> bf16 [B*64, H] ----------------
// Page-sequential streaming: block = (bkk, tensor) owns a CONTIGUOUS 256KB region;
// wave w streams rows [8w, 8w+8) (8 consecutive 4KB pages, consumed start-to-finish).
// Lane l register-accumulates col4 {l, l+64, l+128, l+192}; cross-wave combine via LDS.
__global__ __launch_bounds__(512) void downsample2(const float* __restrict__ key,
                                                   const float* __restrict__ value,
                                                   u16* __restrict__ keyd,
                                                   u16* __restrict__ valued) {
  __shared__ float part[8][256][4];  // 32 KB
  const int bkk = blockIdx.x;
  const float* x = blockIdx.y ? value : key;
  u16* xd = blockIdx.y ? valued : keyd;
  const int t = threadIdx.x, lane = t & 63, w = t >> 6;
  const float* base = x + (size_t)bkk * 65536 + (size_t)w * 8 * 1024;
  float4 acc[4] = {{0.f,0.f,0.f,0.f},{0.f,0.f,0.f,0.f},{0.f,0.f,0.f,0.f},{0.f,0.f,0.f,0.f}};
#pragma unroll
  for (int j = 0; j < 8; ++j) {
#pragma unroll
    for (int s = 0; s < 4; ++s) {
      const float4 v = *(const float4*)(base + (size_t)j * 1024 + (s * 64 + lane) * 4);
      acc[s].x += v.x; acc[s].y += v.y; acc[s].z += v.z; acc[s].w += v.w;
    }
  }
#pragma unroll
  for (int s = 0; s < 4; ++s)
    *(float4*)&part[w][s * 64 + lane][0] = acc[s];
  __syncthreads();
  if (t < 256) {
    float4 s = {0.f, 0.f, 0.f, 0.f};
#pragma unroll
    for (int w2 = 0; w2 < 8; ++w2) {
      const float4 v = *(const float4*)&part[w2][t][0];
      s.x += v.x; s.y += v.y; s.z += v.z; s.w += v.w;
    }
    ushort4 r;
    r.x = f2bf(s.x * 0.015625f);
    r.y = f2bf(s.y * 0.015625f);
    r.z = f2bf(s.z * 0.015625f);
    r.w = f2bf(s.w * 0.015625f);
    *(ushort4*)(xd + (size_t)bkk * 1024 + t * 4) = r;
  }
}

// ---------------- fused small GEMMs (M=256): kd and vd^T in one launch ----------------
__global__ __launch_bounds__(256) void gemm_kv(const u16* __restrict__ A0,
                                               const u16* __restrict__ A1,
                                               const u16* __restrict__ BT0,
                                               const u16* __restrict__ BT1,
                                               const float* __restrict__ bias0,
                                               const float* __restrict__ bias1,
                                               u16* __restrict__ C0,
                                               u16* __restrict__ C1) {
  constexpr int K = 1024, BK = 32;
  __shared__ u16 sA[128 * BK];
  __shared__ u16 sB[128 * BK];
  const int z = blockIdx.z;
  const u16* A = z ? A1 : A0;
  const u16* BT = z ? BT1 : BT0;
  const float* bias = z ? bias1 : bias0;
  u16* Cv = z ? C1 : C0;
  const int t = threadIdx.x;
  const int lane = t & 63;
  const int w = t >> 6;
  const int wr = w >> 1, wc = w & 1;
  const int m0 = blockIdx.x * 128;
  const int n0 = blockIdx.y * 128;
  const int c16 = lane & 15, r16 = lane >> 4;

  f32x4_t acc[4][4] = {};

  for (int k0 = 0; k0 < K; k0 += BK) {
#pragma unroll
    for (int i = 0; i < 2; ++i) {
      const int idx = i * 256 + t;
      const int row = idx >> 2, ch = idx & 3;
      const int gch = ch ^ ((row >> 1) & 3);
      async_load16(A + (size_t)(m0 + row) * K + k0 + gch * 8,
                   (char*)sA + (i * 256 + w * 64) * 16);
    }
#pragma unroll
    for (int i = 0; i < 2; ++i) {
      const int idx = i * 256 + t;
      const int row = idx >> 2, ch = idx & 3;
      const int gch = ch ^ ((row >> 1) & 3);
      async_load16(BT + (size_t)(n0 + row) * K + k0 + gch * 8,
                   (char*)sB + (i * 256 + w * 64) * 16);
    }
    __syncthreads();

    bf16x8_t af[4], bfv[4];
#pragma unroll
    for (int m = 0; m < 4; ++m) {
      const int ra = wr * 64 + m * 16 + c16;
      af[m] = *(const bf16x8_t*)&sA[ra * BK + ((r16 ^ ((ra >> 1) & 3)) << 3)];
    }
#pragma unroll
    for (int n = 0; n < 4; ++n) {
      const int rb = wc * 64 + n * 16 + c16;
      bfv[n] = *(const bf16x8_t*)&sB[rb * BK + ((r16 ^ ((rb >> 1) & 3)) << 3)];
    }
#pragma unroll
    for (int m = 0; m < 4; ++m)
#pragma unroll
      for (int n = 0; n < 4; ++n)
        acc[m][n] = MFMA_BF16(af[m], bfv[n], acc[m][n], 0, 0, 0);
    __syncthreads();
  }

#pragma unroll
  for (int m = 0; m < 4; ++m) {
    const int row0 = m0 + wr * 64 + m * 16 + r16 * 4;
#pragma unroll
    for (int n = 0; n < 4; ++n) {
      const int col = n0 + wc * 64 + n * 16 + c16;
      const float bvl = bias[col];
#pragma unroll
      for (int i = 0; i < 4; ++i) {
        const float val = acc[m][n][i] + bvl;
        if (z)
          Cv[(size_t)col * 256 + row0 + i] = f2bf(val);   // vd^T layout [1024][256]
        else
          Cv[(size_t)(row0 + i) * 1024 + col] = f2bf(val);
      }
    }
  }
}

// ---------------- 256x256 8-phase GEMM: C[16384,1024] = A @ BT^T + bias ----------------
// 512 thr = 8 waves (2M x 4N); per-wave out 128x64; BK=64; LDS 128KB double-buffered.
// Per-thread issue stream (2 global_load_lds per phase), block kt:
//   p0:[kt+1:A2,A3]  p1:[kt+2:A0,A1]  p2:[kt+2:B0,B1]  p3:[kt+2:B2,B3]
// Waits: end-p1 vmcnt(10) (forces [kt:A2,A3]); end-p3 vmcnt(8) (forces K-tile kt+1 fully).
template <bool C_BF16>
__global__ __launch_bounds__(512) void gemm256(const u16* __restrict__ A,
                                               const u16* __restrict__ BT,
                                               const float* __restrict__ bias,
                                               void* __restrict__ Cv) {
  __shared__ u16 sAB[65536];  // 128 KB: [slot][A 32KB | B 32KB]
  char* lds = (char*)sAB;
  const int t = threadIdx.x;
  const int lane = t & 63;
  const int w = t >> 6;
  const int wm = w >> 2, wn = w & 3;
  const int c16 = lane & 15, r16 = lane >> 4, c7 = c16 & 7;

  // XCD swizzle: 256 blocks, XCD x owns bx in [x*8,(x+1)*8) x all 4 by panels
  const int tile = (blockIdx.x & 7) * 32 + (blockIdx.x >> 3);
  const int bx = tile >> 2, by = tile & 3;

  const u16* Ab = A + (size_t)bx * 256 * 1024;
  const u16* Bb = BT + (size_t)by * 256 * 1024;

  // prologue: K0 full (A0,A1,B0..B3,A2,A3) + K1 first 6 (A0,A1,B0..B3)
  stage64(Ab,                      lds,                   t);  // [0:A0] rows 0-63
  stage64(Ab + 128 * 1024,         lds + 128 * 128,       t);  // [0:A1] rows 128-191
  stage64(Bb,                      lds + 32768,           t);  // [0:B0]
  stage64(Bb + 64 * 1024,          lds + 32768 + 8192,    t);
  stage64(Bb + 128 * 1024,         lds + 32768 + 16384,   t);
  stage64(Bb + 192 * 1024,         lds + 32768 + 24576,   t);
  stage64(Ab + 64 * 1024,          lds + 64 * 128,        t);  // [0:A2] rows 64-127
  stage64(Ab + 192 * 1024,         lds + 192 * 128,       t);  // [0:A3] rows 192-255
  stage64(Ab + 64,                 lds + 65536,           t);  // [1:A0]
  stage64(Ab + 128 * 1024 + 64,    lds + 65536 + 16384,   t);  // [1:A1]
  stage64(Bb + 64,                 lds + 98304,           t);  // [1:B0]
  stage64(Bb + 64 * 1024 + 64,     lds + 98304 + 8192,    t);
  stage64(Bb + 128 * 1024 + 64,    lds + 98304 + 16384,   t);
  stage64(Bb + 192 * 1024 + 64,    lds + 98304 + 24576,   t);
  asm volatile("s_waitcnt vmcnt(6)" ::: "memory");  // K0 complete; K1's 6 in flight
  __builtin_amdgcn_s_barrier();

  f32x4_t acc[8][4] = {};
  bf16x8_t bf[4][2];

  for (int kt = 0; kt < 16; ++kt) {
    const int slot = kt & 1;
    const u16* sAs = (const u16*)(lds + slot * 65536);
    const u16* sBs = (const u16*)(lds + slot * 65536 + 32768);
    char* sAn = lds + (slot ^ 1) * 65536;
    char* sAc = lds + slot * 65536;
    char* sBc = lds + slot * 65536 + 32768;
    const int k1 = (kt < 15 ? kt + 1 : 15) * 64;  // clamp keeps vmcnt counts uniform;
    const int k2 = (kt < 14 ? kt + 2 : 15) * 64;  // clamped writes land in dead regions

    bf16x8_t af[4][2];
    // ---------------- phase 0: quadrant (m0-3, n0-1) ----------------
#pragma unroll
    for (int m = 0; m < 4; ++m) {
      const int row = wm * 128 + m * 16 + c16;
#pragma unroll
      for (int kk = 0; kk < 2; ++kk)
        af[m][kk] = *(const bf16x8_t*)&sAs[row * 64 + (((kk * 4 + r16) ^ c7) << 3)];
    }
#pragma unroll
    for (int n = 0; n < 2; ++n) {
      const int row = wn * 64 + n * 16 + c16;
#pragma unroll
      for (int kk = 0; kk < 2; ++kk)
        bf[n][kk] = *(const bf16x8_t*)&sBs[row * 64 + (((kk * 4 + r16) ^ c7) << 3)];
    }
    stage64(Ab + (size_t)64 * 1024 + k1,  sAn + 64 * 128,  t);   // [kt+1:A2]
    stage64(Ab + (size_t)192 * 1024 + k1, sAn + 192 * 128, t);   // [kt+1:A3]
    asm volatile("" ::: "memory");
    __builtin_amdgcn_s_barrier();
    asm volatile("s_waitcnt lgkmcnt(0)" ::: "memory");
    __builtin_amdgcn_sched_barrier(0);
    __builtin_amdgcn_s_setprio(1);
#pragma unroll
    for (int m = 0; m < 4; ++m)
#pragma unroll
      for (int n = 0; n < 2; ++n)
#pragma unroll
        for (int kk = 0; kk < 2; ++kk)
          acc[m][n] = MFMA_BF16(af[m][kk], bf[n][kk], acc[m][n], 0, 0, 0);
    __builtin_amdgcn_s_setprio(0);
    asm volatile("" ::: "memory");
    __builtin_amdgcn_s_barrier();
    // ---------------- phase 1: quadrant (m0-3, n2-3) ----------------
#pragma unroll
    for (int n = 2; n < 4; ++n) {
      const int row = wn * 64 + n * 16 + c16;
#pragma unroll
      for (int kk = 0; kk < 2; ++kk)
        bf[n][kk] = *(const bf16x8_t*)&sBs[row * 64 + (((kk * 4 + r16) ^ c7) << 3)];
    }
    stage64(Ab + k2,                      sAc,             t);   // [kt+2:A0]
    stage64(Ab + (size_t)128 * 1024 + k2, sAc + 128 * 128, t);   // [kt+2:A1]
    asm volatile("" ::: "memory");
    __builtin_amdgcn_s_barrier();
    asm volatile("s_waitcnt lgkmcnt(0)" ::: "memory");
    __builtin_amdgcn_sched_barrier(0);
    __builtin_amdgcn_s_setprio(1);
#pragma unroll
    for (int m = 0; m < 4; ++m)
#pragma unroll
      for (int n = 2; n < 4; ++n)
#pragma unroll
        for (int kk = 0; kk < 2; ++kk)
          acc[m][n] = MFMA_BF16(af[m][kk], bf[n][kk], acc[m][n], 0, 0, 0);
    __builtin_amdgcn_s_setprio(0);
    asm volatile("s_waitcnt vmcnt(10)" ::: "memory");  // forces [kt:A2,A3] done
    __builtin_amdgcn_s_barrier();
    // ---------------- phase 2: quadrant (m4-7, n0-1) ----------------
#pragma unroll
    for (int m = 0; m < 4; ++m) {
      const int row = wm * 128 + 64 + m * 16 + c16;
#pragma unroll
      for (int kk = 0; kk < 2; ++kk)
        af[m][kk] = *(const bf16x8_t*)&sAs[row * 64 + (((kk * 4 + r16) ^ c7) << 3)];
    }
    stage64(Bb + k2,                     sBc,           t);      // [kt+2:B0]
    stage64(Bb + (size_t)64 * 1024 + k2, sBc + 8192,    t);      // [kt+2:B1]
    asm volatile("" ::: "memory");
    __builtin_amdgcn_s_barrier();
    asm volatile("s_waitcnt lgkmcnt(0)" ::: "memory");
    __builtin_amdgcn_sched_barrier(0);
    __builtin_amdgcn_s_setprio(1);
#pragma unroll
    for (int m = 0; m < 4; ++m)
#pragma unroll
      for (int n = 0; n < 2; ++n)
#pragma unroll
        for (int kk = 0; kk < 2; ++kk)
          acc[4 + m][n] = MFMA_BF16(af[m][kk], bf[n][kk], acc[4 + m][n], 0, 0, 0);
    __builtin_amdgcn_s_setprio(0);
    asm volatile("" ::: "memory");
    __builtin_amdgcn_s_barrier();
    // ---------------- phase 3: quadrant (m4-7, n2-3) ----------------
    stage64(Bb + (size_t)128 * 1024 + k2, sBc + 16384, t);       // [kt+2:B2]
    stage64(Bb + (size_t)192 * 1024 + k2, sBc + 24576, t);       // [kt+2:B3]
    asm volatile("" ::: "memory");
    __builtin_amdgcn_s_barrier();
    __builtin_amdgcn_sched_barrier(0);
    __builtin_amdgcn_s_setprio(1);
#pragma unroll
    for (int m = 0; m < 4; ++m)
#pragma unroll
      for (int n = 2; n < 4; ++n)
#pragma unroll
        for (int kk = 0; kk < 2; ++kk)
          acc[4 + m][n] = MFMA_BF16(af[m][kk], bf[n][kk], acc[4 + m][n], 0, 0, 0);
    __builtin_amdgcn_s_setprio(0);
    asm volatile("s_waitcnt vmcnt(8)" ::: "memory");  // forces K-tile kt+1 staged
    __builtin_amdgcn_s_barrier();
  }

  // epilogue
#pragma unroll
  for (int m = 0; m < 8; ++m) {
    const int grow = bx * 256 + wm * 128 + m * 16 + r16 * 4;
#pragma unroll
    for (int n = 0; n < 4; ++n) {
      const int col = by * 256 + wn * 64 + n * 16 + c16;
      const float bvl = bias[col];
#pragma unroll
      for (int i = 0; i < 4; ++i) {
        const float val = acc[m][n][i] + bvl;
        if constexpr (C_BF16)
          ((u16*)Cv)[(size_t)(grow + i) * 1024 + col] = f2bf(val);
        else
          ((float*)Cv)[(size_t)(grow + i) * 1024 + col] = val;
      }
    }
  }
}

// ---------------- MFMA pooled attention ----------------
__global__ __launch_bounds__(256) void attn_mfma(const u16* __restrict__ qb,
                                                 const u16* __restrict__ kdb,
                                                 const u16* __restrict__ vdTb,
                                                 u16* __restrict__ av) {
  __shared__ u16 sKD[64 * 64];
  __shared__ u16 sVD[64 * 64];
  __shared__ u16 sP[4][16 * 64];
  const int t = threadIdx.x;
  const int lane = t & 63;
  const int w = t >> 6;
  const int c16 = lane & 15;
  const int g = lane >> 4;
  const int stile = blockIdx.x, n = blockIdx.y, b = blockIdx.z;
  const int srow_base = b * 4096 + stile * 256 + w * 64;

  bf16x8_t aq[4][2];
#pragma unroll
  for (int st = 0; st < 4; ++st)
#pragma unroll
    for (int dt = 0; dt < 2; ++dt)
      aq[st][dt] = *(const bf16x8_t*)(qb + (size_t)(srow_base + st * 16 + c16) * 1024 +
                                      n * 64 + dt * 32 + g * 8);

#pragma unroll
  for (int c = 0; c < 2; ++c) {
    const int kk = c * 32 + (t >> 3);
    const int colb = ((t & 7) ^ (kk & 7)) << 4;
    async_load16((const char*)kdb + (size_t)(b * 64 + kk) * 2048 + n * 128 + colb,
                 (char*)sKD + c * 4096 + w * 1024);
  }
#pragma unroll
  for (int c = 0; c < 2; ++c) {
    const int dd = c * 32 + (t >> 3);
    const int colb = ((t & 7) ^ (dd & 7)) << 4;
    async_load16((const char*)vdTb + (size_t)(n * 64 + dd) * 512 + b * 128 + colb,
                 (char*)sVD + c * 4096 + w * 1024);
  }
  __syncthreads();

  const int swz = (c16 & 7) << 4;

  for (int st = 0; st < 4; ++st) {
    f32x4_t accs[4];
#pragma unroll
    for (int nn = 0; nn < 4; ++nn) {
      const u16* kr = &sKD[(nn * 16 + c16) * 64];
      bf16x8_t b0 = *(const bf16x8_t*)&kr[((g * 16) ^ swz) >> 1];
      bf16x8_t b1 = *(const bf16x8_t*)&kr[((64 + g * 16) ^ swz) >> 1];
      f32x4_t a = {0.f, 0.f, 0.f, 0.f};
      a = MFMA_BF16(aq[st][0], b0, a, 0, 0, 0);
      a = MFMA_BF16(aq[st][1], b1, a, 0, 0, 0);
      accs[nn] = a;
    }
    float ex[4][4], rs[4];
#pragma unroll
    for (int i = 0; i < 4; ++i) {
      float m = fmaxf(fmaxf(accs[0][i], accs[1][i]), fmaxf(accs[2][i], accs[3][i]));
#pragma unroll
      for (int off = 1; off < 16; off <<= 1) m = fmaxf(m, __shfl_xor(m, off));
      m *= 0.125f;
      float s = 0.f;
#pragma unroll
      for (int nn = 0; nn < 4; ++nn) {
        float e = __expf(accs[nn][i] * 0.125f - m);
        ex[nn][i] = e;
        s += e;
      }
#pragma unroll
      for (int off = 1; off < 16; off <<= 1) s += __shfl_xor(s, off);
      rs[i] = 1.f / s;
    }
#pragma unroll
    for (int i = 0; i < 4; ++i) {
      const int row = g * 4 + i;
      const int rsw = (row & 7) << 4;
#pragma unroll
      for (int nn = 0; nn < 4; ++nn)
        sP[w][row * 64 + (((nn * 32 + c16 * 2) ^ rsw) >> 1)] = f2bf(ex[nn][i]);
    }
    bf16x8_t pa0 = *(const bf16x8_t*)&sP[w][c16 * 64 + (((g * 16) ^ swz) >> 1)];
    bf16x8_t pa1 = *(const bf16x8_t*)&sP[w][c16 * 64 + (((64 + g * 16) ^ swz) >> 1)];
    f32x4_t accv[4];
#pragma unroll
    for (int dt = 0; dt < 4; ++dt) {
      const u16* vr = &sVD[(dt * 16 + c16) * 64];
      bf16x8_t v0 = *(const bf16x8_t*)&vr[((g * 16) ^ swz) >> 1];
      bf16x8_t v1 = *(const bf16x8_t*)&vr[((64 + g * 16) ^ swz) >> 1];
      f32x4_t a = {0.f, 0.f, 0.f, 0.f};
      a = MFMA_BF16(pa0, v0, a, 0, 0, 0);
      a = MFMA_BF16(pa1, v1, a, 0, 0, 0);
      accv[dt] = a;
    }
#pragma unroll
    for (int i = 0; i < 4; ++i) {
      const int row = g * 4 + i;
      const int rsw = (row & 7) << 4;
#pragma unroll
      for (int dt = 0; dt < 4; ++dt)
        sP[w][row * 64 + (((dt * 32 + c16 * 2) ^ rsw) >> 1)] = f2bf(accv[dt][i] * rs[i]);
    }
#pragma unroll
    for (int r = 0; r < 2; ++r) {
      const int row = r * 8 + (lane >> 3);
      const int cb = ((lane & 7) * 16) ^ ((row & 7) << 4);
      bf16x8_t vv = *(const bf16x8_t*)&sP[w][row * 64 + (cb >> 1)];
      *(bf16x8_t*)(av + (size_t)(srow_base + st * 16 + row) * 1024 + n * 64 + (lane & 7) * 8) = vv;
    }
  }
}

extern "C" void kernel_launch(void* const* d_in, const int* in_sizes, int n_in,
                              void* d_out, int out_size, void* d_ws, size_t ws_size,
                              hipStream_t stream) {
  (void)in_sizes; (void)n_in; (void)out_size; (void)ws_size;
  const float* query = (const float*)d_in[0];
  const float* key   = (const float*)d_in[1];
  const float* value = (const float*)d_in[2];
  const float* Wq = (const float*)d_in[3];
  const float* bq = (const float*)d_in[4];
  const float* Wk = (const float*)d_in[5];
  const float* bk = (const float*)d_in[6];
  const float* Wv = (const float*)d_in[7];
  const float* bv = (const float*)d_in[8];
  const float* Wo = (const float*)d_in[9];
  const float* bo = (const float*)d_in[10];
  float* out = (float*)d_out;

  char* ws = (char*)d_ws;
  const size_t MB = 1024 * 1024;
  u16* WqT    = (u16*)(ws + 0 * MB);
  u16* WkT    = (u16*)(ws + 2 * MB);
  u16* WvT    = (u16*)(ws + 4 * MB);
  u16* WoT    = (u16*)(ws + 6 * MB);
  u16* keyd   = (u16*)(ws + 8 * MB);
  u16* valued = (u16*)(ws + 8 * MB + 512 * 1024);
  u16* kdb    = (u16*)(ws + 9 * MB);
  u16* vdTb   = (u16*)(ws + 9 * MB + 512 * 1024);
  u16* avb    = (u16*)(ws + 10 * MB);             // 32MB bf16 [16384][1024]
  u16* qbuf   = (u16*)d_out;                      // lo 32MB of d_out
  u16* qcvt   = (u16*)((char*)d_out + 32 * MB);   // hi 32MB of d_out

  dim3 blk(256);

  cvt_bf16<<<8192, blk, 0, stream>>>(query, qcvt);
  transpose_w4<<<dim3(16, 16, 4), blk, 0, stream>>>(Wq, Wk, Wv, Wo, WqT, WkT, WvT, WoT);
  downsample2<<<dim3(256, 2), 512, 0, stream>>>(key, value, keyd, valued);

  gemm_kv<<<dim3(2, 8, 2), blk, 0, stream>>>(keyd, valued, WkT, WvT, bk, bv, kdb, vdTb);

  gemm256<true><<<256, 512, 0, stream>>>(qcvt, WqT, bq, qbuf);
  attn_mfma<<<dim3(16, 16, 4), blk, 0, stream>>>(qbuf, kdb, vdTb, avb);
  gemm256<false><<<256, 512, 0, stream>>>(avb, WoT, bo, out);
}